// Round 2
// baseline (2388.103 us; speedup 1.0000x reference)
//
#include <hip/hip_runtime.h>
#include <math.h>

#define NA 100000
#define NB 100000
#define NTOT 200000
#define EE 400000      // edges per type
#define TDIM 100       // time encoder dim

// ---------- helpers ----------
__device__ __forceinline__ unsigned fmap(float f) {
    unsigned u = __float_as_uint(f);
    return (u & 0x80000000u) ? ~u : (u | 0x80000000u);
}
__device__ __forceinline__ float funmap(unsigned u) {
    return (u & 0x80000000u) ? __uint_as_float(u ^ 0x80000000u) : __uint_as_float(~u);
}
__device__ __forceinline__ float gelu_exact(float x) {
    return 0.5f * x * (1.0f + erff(x * 0.70710678118654752f));
}

// ---------- K1: kqv = x@W_kqv + b, then per-head rel transform of k and v ----------
#define KQN 32
__global__ __launch_bounds__(384) void kqv_kernel(
    const float* __restrict__ x, const float* __restrict__ W, const float* __restrict__ bias,
    const float* __restrict__ Wk_rel, const float* __restrict__ Wv_rel,
    float* __restrict__ q_out, float* __restrict__ k_out, float* __restrict__ v_out,
    int N, int et, int node_off)
{
    __shared__ float xs[KQN * 128];
    __shared__ float ks[KQN * 128];
    __shared__ float vs[KQN * 128];
    const int tid = threadIdx.x;
    const int n0 = blockIdx.x * KQN;
    const int nn = min(KQN, N - n0);

    for (int i = tid; i < nn * 128; i += 384) xs[i] = x[(long)n0 * 128 + i];
    __syncthreads();

    {
        const int c = tid;                       // output column 0..383
        float acc[KQN];
        const float bc = bias[c];
        #pragma unroll
        for (int n = 0; n < KQN; ++n) acc[n] = bc;
        for (int d4 = 0; d4 < 32; ++d4) {
            const float w0 = W[(d4 * 4 + 0) * 384 + c];
            const float w1 = W[(d4 * 4 + 1) * 384 + c];
            const float w2 = W[(d4 * 4 + 2) * 384 + c];
            const float w3 = W[(d4 * 4 + 3) * 384 + c];
            #pragma unroll
            for (int n = 0; n < KQN; ++n) {
                const float4 xv = *reinterpret_cast<const float4*>(&xs[n * 128 + d4 * 4]);
                acc[n] = fmaf(xv.x, w0, fmaf(xv.y, w1, fmaf(xv.z, w2, fmaf(xv.w, w3, acc[n]))));
            }
        }
        if (c < 128) {                           // k -> LDS for rel transform
            for (int n = 0; n < nn; ++n) ks[n * 128 + c] = acc[n];
        } else if (c < 256) {                    // q -> global directly
            for (int n = 0; n < nn; ++n) q_out[(long)(node_off + n0 + n) * 128 + (c - 128)] = acc[n];
        } else {                                 // v -> LDS
            for (int n = 0; n < nn; ++n) vs[n * 128 + (c - 256)] = acc[n];
        }
    }
    __syncthreads();

    if (tid < 256) {
        const int grp = tid >> 7;                // 0 -> k, 1 -> v
        const int sub = tid & 127;
        const int h = sub >> 6, e2 = sub & 63;
        const float* __restrict__ Wr = (grp == 0 ? Wk_rel : Wv_rel) + (long)(h * 2 + et) * 4096;
        const float* __restrict__ sbuf = (grp == 0 ? ks : vs);
        float acc2[KQN];
        #pragma unroll
        for (int n = 0; n < KQN; ++n) acc2[n] = 0.f;
        for (int d4 = 0; d4 < 16; ++d4) {
            const float w0 = Wr[(d4 * 4 + 0) * 64 + e2];
            const float w1 = Wr[(d4 * 4 + 1) * 64 + e2];
            const float w2 = Wr[(d4 * 4 + 2) * 64 + e2];
            const float w3 = Wr[(d4 * 4 + 3) * 64 + e2];
            #pragma unroll
            for (int n = 0; n < KQN; ++n) {
                const float4 xv = *reinterpret_cast<const float4*>(&sbuf[n * 128 + h * 64 + d4 * 4]);
                acc2[n] = fmaf(xv.x, w0, fmaf(xv.y, w1, fmaf(xv.z, w2, fmaf(xv.w, w3, acc2[n]))));
            }
        }
        float* __restrict__ dp = (grp == 0 ? k_out : v_out);
        for (int n = 0; n < nn; ++n) dp[(long)(node_off + n0 + n) * 128 + sub] = acc2[n];
    }
}

// ---------- K2: raw attention logits + atomic segment max ----------
__global__ __launch_bounds__(256) void alpha_kernel(
    const float* __restrict__ q, const float* __restrict__ k_src,
    const int* __restrict__ eiAB, const int* __restrict__ eiBA,
    const float* __restrict__ p_rel_AB, const float* __restrict__ p_rel_BA,
    float* __restrict__ alpha, unsigned* __restrict__ m_u)
{
    const int lane = threadIdx.x & 63;
    const int wid = blockIdx.x * 4 + (threadIdx.x >> 6);
    const int nw = gridDim.x * 4;
    const float pAB0 = p_rel_AB[0], pAB1 = p_rel_AB[1];
    const float pBA0 = p_rel_BA[0], pBA1 = p_rel_BA[1];
    for (int ee = wid; ee < 2 * EE; ee += nw) {
        int src, dst; float p0, p1;
        if (ee < EE) { src = eiAB[ee];           dst = eiAB[EE + ee] + NA; p0 = pAB0; p1 = pAB1; }
        else { const int e = ee - EE; src = eiBA[e] + NA; dst = eiBA[EE + e]; p0 = pBA0; p1 = pBA1; }
        const float q0 = q[(long)dst * 128 + lane];
        const float q1 = q[(long)dst * 128 + 64 + lane];
        const float k0 = k_src[(long)src * 128 + lane];
        const float k1 = k_src[(long)src * 128 + 64 + lane];
        float s0 = q0 * k0, s1 = q1 * k1;
        #pragma unroll
        for (int off = 32; off > 0; off >>= 1) {
            s0 += __shfl_xor(s0, off, 64);
            s1 += __shfl_xor(s1, off, 64);
        }
        if (lane == 0) {
            const float a0 = s0 * p0 * 0.125f;
            const float a1 = s1 * p1 * 0.125f;
            alpha[(long)ee * 2 + 0] = a0;
            alpha[(long)ee * 2 + 1] = a1;
            atomicMax(&m_u[dst * 2 + 0], fmap(a0));
            atomicMax(&m_u[dst * 2 + 1], fmap(a1));
        }
    }
}

// ---------- K3: exp(alpha - m), atomic segment sum ----------
__global__ __launch_bounds__(256) void expsum_kernel(
    const int* __restrict__ eiAB, const int* __restrict__ eiBA,
    float* __restrict__ alpha, const unsigned* __restrict__ m_u,
    float* __restrict__ ssum)
{
    const long stride = (long)gridDim.x * blockDim.x;
    for (long i = (long)blockIdx.x * blockDim.x + threadIdx.x; i < 4L * EE; i += stride) {
        const int ee = (int)(i >> 1), h = (int)(i & 1);
        int dst;
        if (ee < EE) dst = eiAB[EE + ee] + NA;
        else         dst = eiBA[EE + (ee - EE)];
        const float m = funmap(m_u[dst * 2 + h]);
        const float v = expf(alpha[i] - m);
        alpha[i] = v;
        atomicAdd(&ssum[dst * 2 + h], v);
    }
}

// ---------- K4: fused edge-feature GEMM + weighted scatter ----------
// block = 32 edges; computes ef = cat([cos(rel_t*tw+tb), msg]) @ W_edge + b_edge
// in LDS, then atomically accumulates [v_j | ef] * alpha/ssum into out_acc.
#define SFN 32
__global__ __launch_bounds__(256) void fused_scatter_kernel(
    const float* __restrict__ lu_A, const float* __restrict__ lu_B,
    const float* __restrict__ t_AB, const float* __restrict__ t_BA,
    const float* __restrict__ msg_AB, const float* __restrict__ msg_BA,
    const int* __restrict__ eiAB, const int* __restrict__ eiBA,
    const float* __restrict__ time_w, const float* __restrict__ time_b,
    const float* __restrict__ W_edge, const float* __restrict__ b_edge,
    const float* __restrict__ v_src, const float* __restrict__ alpha,
    const float* __restrict__ ssum, float* __restrict__ out_acc)
{
    __shared__ float feat[SFN][164];   // 656 B/row, 16B-aligned rows
    __shared__ float efl[SFN][64];
    __shared__ float rts[SFN];
    __shared__ int s_src[SFN];
    __shared__ int s_dst[SFN];
    __shared__ float s_coef[SFN][2];

    const int tid = threadIdx.x;
    const int lane = tid & 63;
    const int wv = tid >> 6;
    const long e0 = (long)blockIdx.x * SFN;          // [0, 2E); 400000 % 32 == 0, no straddle
    const bool isAB = (e0 < EE);
    const float* __restrict__ lu  = isAB ? lu_A : lu_B;
    const float* __restrict__ tv  = isAB ? t_AB : t_BA;
    const float* __restrict__ msg = isAB ? msg_AB : msg_BA;
    const int*   __restrict__ ei  = isAB ? eiAB : eiBA;
    const long eb = isAB ? e0 : (e0 - EE);           // base within edge type

    if (tid < SFN) {
        const long e = eb + tid;
        const int s = ei[e];
        const int d = ei[EE + e];
        const int src = isAB ? s : (s + NA);
        const int dst = isAB ? (d + NA) : d;
        s_src[tid] = src;
        s_dst[tid] = dst;
        rts[tid] = lu[s] - tv[e];
        const long ee = e0 + tid;
        s_coef[tid][0] = alpha[ee * 2 + 0] / (ssum[dst * 2 + 0] + 1e-16f);
        s_coef[tid][1] = alpha[ee * 2 + 1] / (ssum[dst * 2 + 1] + 1e-16f);
    }
    __syncthreads();
    for (int i = tid; i < SFN * TDIM; i += 256) {
        const int e = i / TDIM, j = i - e * TDIM;
        feat[e][j] = cosf(rts[e] * time_w[j] + time_b[j]);
    }
    for (int i = tid; i < SFN * 64; i += 256) {
        const int e = i >> 6, j = i & 63;
        feat[e][TDIM + j] = msg[(eb + e) * 64 + j];
    }
    __syncthreads();

    // ef GEMM: wave wv -> edges wv*8..wv*8+7, lane = out column
    {
        float acc[8];
        const float bc = b_edge[lane];
        #pragma unroll
        for (int k = 0; k < 8; ++k) acc[k] = bc;
        for (int t4 = 0; t4 < 41; ++t4) {
            const float w0 = W_edge[(t4 * 4 + 0) * 64 + lane];
            const float w1 = W_edge[(t4 * 4 + 1) * 64 + lane];
            const float w2 = W_edge[(t4 * 4 + 2) * 64 + lane];
            const float w3 = W_edge[(t4 * 4 + 3) * 64 + lane];
            #pragma unroll
            for (int k = 0; k < 8; ++k) {
                const float4 fv = *reinterpret_cast<const float4*>(&feat[wv * 8 + k][t4 * 4]);
                acc[k] = fmaf(fv.x, w0, fmaf(fv.y, w1, fmaf(fv.z, w2, fmaf(fv.w, w3, acc[k]))));
            }
        }
        #pragma unroll
        for (int k = 0; k < 8; ++k) efl[wv * 8 + k][lane] = acc[k];
    }
    __syncthreads();

    // scatter: wave wv -> edges wv*8..wv*8+7; lane covers cols {lane, 64+lane, 128+lane, 192+lane}
    #pragma unroll
    for (int k = 0; k < 8; ++k) {
        const int e = wv * 8 + k;
        const int src = s_src[e];
        const long dbase = (long)s_dst[e] * 256;
        const float c0 = s_coef[e][0];
        const float c1 = s_coef[e][1];
        const float v0 = v_src[(long)src * 128 + lane];
        const float v1 = v_src[(long)src * 128 + 64 + lane];
        const float ev = efl[e][lane];
        atomicAdd(&out_acc[dbase + lane],       v0 * c0);
        atomicAdd(&out_acc[dbase + 64 + lane],  ev * c0);
        atomicAdd(&out_acc[dbase + 128 + lane], v1 * c1);
        atomicAdd(&out_acc[dbase + 192 + lane], ev * c1);
    }
}

// ---------- K5: out = skip-gated( gelu(acc) @ W_out + b ) ----------
#define OPN 32
__global__ __launch_bounds__(128) void outproj_kernel(
    const float* __restrict__ out_acc, const float* __restrict__ W_out, const float* __restrict__ b_out,
    const float* __restrict__ x, const float* __restrict__ skip,
    float* __restrict__ outp, int N, int acc_off)
{
    __shared__ float gs[OPN * 256];
    const int tid = threadIdx.x;      // 0..127 output column
    const int n0 = blockIdx.x * OPN;
    const int nn = min(OPN, N - n0);
    for (int i = tid; i < nn * 256; i += 128) {
        gs[i] = gelu_exact(out_acc[((long)(acc_off + n0)) * 256 + i]);
    }
    __syncthreads();
    const float a = 1.f / (1.f + expf(-skip[0]));
    float acc[OPN];
    const float bc = b_out[tid];
    #pragma unroll
    for (int n = 0; n < OPN; ++n) acc[n] = bc;
    for (int d4 = 0; d4 < 64; ++d4) {
        const float w0 = W_out[(d4 * 4 + 0) * 128 + tid];
        const float w1 = W_out[(d4 * 4 + 1) * 128 + tid];
        const float w2 = W_out[(d4 * 4 + 2) * 128 + tid];
        const float w3 = W_out[(d4 * 4 + 3) * 128 + tid];
        #pragma unroll
        for (int n = 0; n < OPN; ++n) {
            const float4 g = *reinterpret_cast<const float4*>(&gs[n * 256 + d4 * 4]);
            acc[n] = fmaf(g.x, w0, fmaf(g.y, w1, fmaf(g.z, w2, fmaf(g.w, w3, acc[n]))));
        }
    }
    for (int n = 0; n < nn; ++n) {
        const float xv = x[(long)(n0 + n) * 128 + tid];
        outp[(long)(n0 + n) * 128 + tid] = a * acc[n] + (1.f - a) * xv;
    }
}

// ---------- launcher ----------
extern "C" void kernel_launch(void* const* d_in, const int* in_sizes, int n_in,
                              void* d_out, int out_size, void* d_ws, size_t ws_size,
                              hipStream_t stream) {
    const float* x_A     = (const float*)d_in[0];
    const float* x_B     = (const float*)d_in[1];
    const float* lu_A    = (const float*)d_in[2];
    const float* lu_B    = (const float*)d_in[3];
    const float* t_AB    = (const float*)d_in[4];
    const float* t_BA    = (const float*)d_in[5];
    const float* msg_AB  = (const float*)d_in[6];
    const float* msg_BA  = (const float*)d_in[7];
    const float* W_kqv_A = (const float*)d_in[8];
    const float* b_kqv_A = (const float*)d_in[9];
    const float* W_kqv_B = (const float*)d_in[10];
    const float* b_kqv_B = (const float*)d_in[11];
    const float* Wk_rel  = (const float*)d_in[12];
    const float* Wv_rel  = (const float*)d_in[13];
    const float* W_edge  = (const float*)d_in[14];
    const float* b_edge  = (const float*)d_in[15];
    const float* W_out_A = (const float*)d_in[16];
    const float* b_out_A = (const float*)d_in[17];
    const float* W_out_B = (const float*)d_in[18];
    const float* b_out_B = (const float*)d_in[19];
    const float* skip_A  = (const float*)d_in[20];
    const float* skip_B  = (const float*)d_in[21];
    const float* p_rel_AB= (const float*)d_in[22];
    const float* p_rel_BA= (const float*)d_in[23];
    const float* time_w  = (const float*)d_in[24];
    const float* time_b  = (const float*)d_in[25];
    const int*   eiAB    = (const int*)d_in[26];
    const int*   eiBA    = (const int*)d_in[27];
    float* out = (float*)d_out;

    // workspace layout (floats), total 79.2M floats = 316.8 MB:
    //   v_src  [ 0.0M .. 25.6M)
    //   q      [25.6M .. 51.2M)   -- dead after alpha_kernel
    //   k_src  [51.2M .. 76.8M)   -- dead after alpha_kernel
    //   out_acc ALIASES q+k       [25.6M .. 76.8M), zeroed after expsum
    //   alpha  [76.8M .. 78.4M)
    //   m_u    [78.4M .. 78.8M)
    //   ssum   [78.8M .. 79.2M)
    float* v_src   = (float*)d_ws;
    float* q       = v_src + 25600000;
    float* k_src   = q + 25600000;
    float* out_acc = q;                            // alias: q + k region (51.2M floats)
    float* alpha   = k_src + 25600000;
    unsigned* m_u  = (unsigned*)(alpha + 1600000);
    float* ssum    = (float*)(m_u + 400000);

    // zero m_u (0 == "-inf" sentinel in mapped-uint space) and ssum
    hipMemsetAsync(m_u, 0, (size_t)800000 * 4, stream);

    kqv_kernel<<<(NA + KQN - 1) / KQN, 384, 0, stream>>>(x_A, W_kqv_A, b_kqv_A, Wk_rel, Wv_rel,
                                                         q, k_src, v_src, NA, 0, 0);
    kqv_kernel<<<(NB + KQN - 1) / KQN, 384, 0, stream>>>(x_B, W_kqv_B, b_kqv_B, Wk_rel, Wv_rel,
                                                         q, k_src, v_src, NB, 1, NA);
    alpha_kernel<<<8192, 256, 0, stream>>>(q, k_src, eiAB, eiBA, p_rel_AB, p_rel_BA, alpha, m_u);
    expsum_kernel<<<6400, 256, 0, stream>>>(eiAB, eiBA, alpha, m_u, ssum);
    // q, k_src now dead -> reuse their space as the 200000x256 accumulator
    hipMemsetAsync(out_acc, 0, (size_t)51200000 * 4, stream);
    fused_scatter_kernel<<<2 * EE / SFN, 256, 0, stream>>>(lu_A, lu_B, t_AB, t_BA, msg_AB, msg_BA,
                                                           eiAB, eiBA, time_w, time_b, W_edge, b_edge,
                                                           v_src, alpha, ssum, out_acc);
    outproj_kernel<<<(NA + OPN - 1) / OPN, 128, 0, stream>>>(out_acc, W_out_A, b_out_A, x_A, skip_A,
                                                             out, NA, 0);
    outproj_kernel<<<(NB + OPN - 1) / OPN, 128, 0, stream>>>(out_acc, W_out_B, b_out_B, x_B, skip_B,
                                                             out + (long)NA * 128, NB, NA);
}

// Round 3
// 2373.275 us; speedup vs baseline: 1.0062x; 1.0062x over previous
//
#include <hip/hip_runtime.h>
#include <math.h>

#define NA 100000
#define NB 100000
#define NTOT 200000
#define EE 400000      // edges per type
#define TDIM 100       // time encoder dim

// ---------- helpers ----------
__device__ __forceinline__ unsigned fmap(float f) {
    unsigned u = __float_as_uint(f);
    return (u & 0x80000000u) ? ~u : (u | 0x80000000u);
}
__device__ __forceinline__ float funmap(unsigned u) {
    return (u & 0x80000000u) ? __uint_as_float(u ^ 0x80000000u) : __uint_as_float(~u);
}
__device__ __forceinline__ float gelu_exact(float x) {
    return 0.5f * x * (1.0f + erff(x * 0.70710678118654752f));
}
__device__ __forceinline__ float readlanef(float v, int l) {
    return __int_as_float(__builtin_amdgcn_readlane(__float_as_int(v), l));
}

// ---------- K1: kqv = x@W_kqv + b, then per-head rel transform of k and v ----------
#define KQN 32
__global__ __launch_bounds__(384) void kqv_kernel(
    const float* __restrict__ x, const float* __restrict__ W, const float* __restrict__ bias,
    const float* __restrict__ Wk_rel, const float* __restrict__ Wv_rel,
    float* __restrict__ q_out, float* __restrict__ k_out, float* __restrict__ v_out,
    int N, int et, int node_off)
{
    __shared__ float xs[KQN * 128];
    __shared__ float ks[KQN * 128];
    __shared__ float vs[KQN * 128];
    const int tid = threadIdx.x;
    const int n0 = blockIdx.x * KQN;
    const int nn = min(KQN, N - n0);

    for (int i = tid; i < nn * 128; i += 384) xs[i] = x[(long)n0 * 128 + i];
    __syncthreads();

    {
        const int c = tid;                       // output column 0..383
        float acc[KQN];
        const float bc = bias[c];
        #pragma unroll
        for (int n = 0; n < KQN; ++n) acc[n] = bc;
        for (int d4 = 0; d4 < 32; ++d4) {
            const float w0 = W[(d4 * 4 + 0) * 384 + c];
            const float w1 = W[(d4 * 4 + 1) * 384 + c];
            const float w2 = W[(d4 * 4 + 2) * 384 + c];
            const float w3 = W[(d4 * 4 + 3) * 384 + c];
            #pragma unroll
            for (int n = 0; n < KQN; ++n) {
                const float4 xv = *reinterpret_cast<const float4*>(&xs[n * 128 + d4 * 4]);
                acc[n] = fmaf(xv.x, w0, fmaf(xv.y, w1, fmaf(xv.z, w2, fmaf(xv.w, w3, acc[n]))));
            }
        }
        if (c < 128) {                           // k -> LDS for rel transform
            for (int n = 0; n < nn; ++n) ks[n * 128 + c] = acc[n];
        } else if (c < 256) {                    // q -> global directly
            for (int n = 0; n < nn; ++n) q_out[(long)(node_off + n0 + n) * 128 + (c - 128)] = acc[n];
        } else {                                 // v -> LDS
            for (int n = 0; n < nn; ++n) vs[n * 128 + (c - 256)] = acc[n];
        }
    }
    __syncthreads();

    if (tid < 256) {
        const int grp = tid >> 7;                // 0 -> k, 1 -> v
        const int sub = tid & 127;
        const int h = sub >> 6, e2 = sub & 63;
        const float* __restrict__ Wr = (grp == 0 ? Wk_rel : Wv_rel) + (long)(h * 2 + et) * 4096;
        const float* __restrict__ sbuf = (grp == 0 ? ks : vs);
        float acc2[KQN];
        #pragma unroll
        for (int n = 0; n < KQN; ++n) acc2[n] = 0.f;
        for (int d4 = 0; d4 < 16; ++d4) {
            const float w0 = Wr[(d4 * 4 + 0) * 64 + e2];
            const float w1 = Wr[(d4 * 4 + 1) * 64 + e2];
            const float w2 = Wr[(d4 * 4 + 2) * 64 + e2];
            const float w3 = Wr[(d4 * 4 + 3) * 64 + e2];
            #pragma unroll
            for (int n = 0; n < KQN; ++n) {
                const float4 xv = *reinterpret_cast<const float4*>(&sbuf[n * 128 + h * 64 + d4 * 4]);
                acc2[n] = fmaf(xv.x, w0, fmaf(xv.y, w1, fmaf(xv.z, w2, fmaf(xv.w, w3, acc2[n]))));
            }
        }
        float* __restrict__ dp = (grp == 0 ? k_out : v_out);
        for (int n = 0; n < nn; ++n) dp[(long)(node_off + n0 + n) * 128 + sub] = acc2[n];
    }
}

// ---------- K2: raw attention logits + atomic segment max ----------
__global__ __launch_bounds__(256) void alpha_kernel(
    const float* __restrict__ q, const float* __restrict__ k_src,
    const int* __restrict__ eiAB, const int* __restrict__ eiBA,
    const float* __restrict__ p_rel_AB, const float* __restrict__ p_rel_BA,
    float* __restrict__ alpha, unsigned* __restrict__ m_u)
{
    const int lane = threadIdx.x & 63;
    const int wid = blockIdx.x * 4 + (threadIdx.x >> 6);
    const int nw = gridDim.x * 4;
    const float pAB0 = p_rel_AB[0], pAB1 = p_rel_AB[1];
    const float pBA0 = p_rel_BA[0], pBA1 = p_rel_BA[1];
    for (int ee = wid; ee < 2 * EE; ee += nw) {
        int src, dst; float p0, p1;
        if (ee < EE) { src = eiAB[ee];           dst = eiAB[EE + ee] + NA; p0 = pAB0; p1 = pAB1; }
        else { const int e = ee - EE; src = eiBA[e] + NA; dst = eiBA[EE + e]; p0 = pBA0; p1 = pBA1; }
        const float q0 = q[(long)dst * 128 + lane];
        const float q1 = q[(long)dst * 128 + 64 + lane];
        const float k0 = k_src[(long)src * 128 + lane];
        const float k1 = k_src[(long)src * 128 + 64 + lane];
        float s0 = q0 * k0, s1 = q1 * k1;
        #pragma unroll
        for (int off = 32; off > 0; off >>= 1) {
            s0 += __shfl_xor(s0, off, 64);
            s1 += __shfl_xor(s1, off, 64);
        }
        if (lane == 0) {
            const float a0 = s0 * p0 * 0.125f;
            const float a1 = s1 * p1 * 0.125f;
            alpha[(long)ee * 2 + 0] = a0;
            alpha[(long)ee * 2 + 1] = a1;
            atomicMax(&m_u[dst * 2 + 0], fmap(a0));
            atomicMax(&m_u[dst * 2 + 1], fmap(a1));
        }
    }
}

// ---------- K3: exp(alpha - m), atomic segment sum ----------
__global__ __launch_bounds__(256) void expsum_kernel(
    const int* __restrict__ eiAB, const int* __restrict__ eiBA,
    float* __restrict__ alpha, const unsigned* __restrict__ m_u,
    float* __restrict__ ssum)
{
    const long stride = (long)gridDim.x * blockDim.x;
    for (long i = (long)blockIdx.x * blockDim.x + threadIdx.x; i < 4L * EE; i += stride) {
        const int ee = (int)(i >> 1), h = (int)(i & 1);
        int dst;
        if (ee < EE) dst = eiAB[EE + ee] + NA;
        else         dst = eiBA[EE + (ee - EE)];
        const float m = funmap(m_u[dst * 2 + h]);
        const float v = expf(alpha[i] - m);
        alpha[i] = v;
        atomicAdd(&ssum[dst * 2 + h], v);
    }
}

// ---------- K4: edge_feat = cat([cos(rel_t*tw+tb), msg]) @ W_edge + b_edge ----------
#define EFN 32
__global__ __launch_bounds__(256) void edgefeat_kernel(
    const float* __restrict__ last_update, const int* __restrict__ ei,
    const float* __restrict__ tvec, const float* __restrict__ msg,
    const float* __restrict__ time_w, const float* __restrict__ time_b,
    const float* __restrict__ W_edge, const float* __restrict__ b_edge,
    float* __restrict__ ef_out, int E, long out_off)
{
    __shared__ float feat[EFN][164];
    __shared__ float rts[EFN];
    const int tid = threadIdx.x;
    const int lane = tid & 63;
    const int wv = tid >> 6;
    const int e0 = blockIdx.x * EFN;
    const int ne = min(EFN, E - e0);

    for (int e = tid; e < ne; e += 256) rts[e] = last_update[ei[e0 + e]] - tvec[e0 + e];
    __syncthreads();
    for (int i = tid; i < ne * TDIM; i += 256) {
        const int e = i / TDIM, j = i - e * TDIM;
        feat[e][j] = cosf(rts[e] * time_w[j] + time_b[j]);
    }
    for (int i = tid; i < ne * 64; i += 256) {
        const int e = i >> 6, j = i & 63;
        feat[e][TDIM + j] = msg[(long)(e0 + e) * 64 + j];
    }
    __syncthreads();

    float acc[8];
    const float bc = b_edge[lane];
    #pragma unroll
    for (int k = 0; k < 8; ++k) acc[k] = bc;
    for (int t4 = 0; t4 < 41; ++t4) {
        const float w0 = W_edge[(t4 * 4 + 0) * 64 + lane];
        const float w1 = W_edge[(t4 * 4 + 1) * 64 + lane];
        const float w2 = W_edge[(t4 * 4 + 2) * 64 + lane];
        const float w3 = W_edge[(t4 * 4 + 3) * 64 + lane];
        #pragma unroll
        for (int k = 0; k < 8; ++k) {
            const float4 fv = *reinterpret_cast<const float4*>(&feat[wv * 8 + k][t4 * 4]);
            acc[k] = fmaf(fv.x, w0, fmaf(fv.y, w1, fmaf(fv.z, w2, fmaf(fv.w, w3, acc[k]))));
        }
    }
    #pragma unroll
    for (int k = 0; k < 8; ++k) {
        const int e = wv * 8 + k;
        if (e < ne) ef_out[(out_off + e0 + e) * 64 + lane] = acc[k];
    }
}

// ---------- CSR build ----------
__global__ __launch_bounds__(256) void count_kernel(
    const int* __restrict__ eiAB, const int* __restrict__ eiBA, int* __restrict__ cnt)
{
    const int ee = blockIdx.x * 256 + threadIdx.x;
    if (ee >= 2 * EE) return;
    const int dst = (ee < EE) ? (eiAB[EE + ee] + NA) : eiBA[EE + (ee - EE)];
    atomicAdd(&cnt[dst], 1);
}

#define SCHUNK 196   // 1024*196 = 200704 >= NTOT
__global__ __launch_bounds__(1024) void scan_kernel(int* __restrict__ cnt, int* __restrict__ offsets)
{
    __shared__ int part[1024];
    const int t = threadIdx.x;
    const int base = t * SCHUNK;
    const int n = max(0, min(SCHUNK, NTOT - base));
    int s = 0;
    for (int i = 0; i < n; ++i) s += cnt[base + i];
    part[t] = s;
    __syncthreads();
    for (int off = 1; off < 1024; off <<= 1) {
        const int v = (t >= off) ? part[t - off] : 0;
        __syncthreads();
        part[t] += v;
        __syncthreads();
    }
    int run = part[t] - s;                 // exclusive prefix
    for (int i = 0; i < n; ++i) {
        const int c = cnt[base + i];
        offsets[base + i] = run;
        cnt[base + i] = run;               // becomes the fill cursor
        run += c;
    }
    if (t == 1023) offsets[NTOT] = part[1023];
}

__global__ __launch_bounds__(256) void fill_kernel(
    const int* __restrict__ eiAB, const int* __restrict__ eiBA,
    int* __restrict__ cursor, int* __restrict__ csr_src, int* __restrict__ csr_ee)
{
    const int ee = blockIdx.x * 256 + threadIdx.x;
    if (ee >= 2 * EE) return;
    int src, dst;
    if (ee < EE) { src = eiAB[ee];               dst = eiAB[EE + ee] + NA; }
    else { const int e = ee - EE; src = eiBA[e] + NA; dst = eiBA[EE + e]; }
    const int pos = atomicAdd(&cursor[dst], 1);
    csr_src[pos] = src;
    csr_ee[pos] = ee;
}

// ---------- K5: fused CSR aggregate + gelu + out-projection + gated skip ----------
// one wave per 8 dst rows; projection via v_readlane broadcast (no LDS)
__global__ __launch_bounds__(256) void agg_proj_kernel(
    const float* __restrict__ v_src, const float* __restrict__ ef,
    const float* __restrict__ alpha, const float* __restrict__ ssum,
    const int* __restrict__ offsets, const int* __restrict__ csr_src, const int* __restrict__ csr_ee,
    const float* __restrict__ W_out_A, const float* __restrict__ b_out_A,
    const float* __restrict__ W_out_B, const float* __restrict__ b_out_B,
    const float* __restrict__ x_A, const float* __restrict__ x_B,
    const float* __restrict__ skip_A, const float* __restrict__ skip_B,
    float* __restrict__ out)
{
    const int lane = threadIdx.x & 63;
    const int wv = threadIdx.x >> 6;
    const int row0 = blockIdx.x * 32 + wv * 8;       // 3125 blocks = A side (rows < 100000)
    const bool isA = row0 < NA;
    const float* __restrict__ W  = isA ? W_out_A : W_out_B;
    const float* __restrict__ bo = isA ? b_out_A : b_out_B;
    const float* __restrict__ xs = isA ? x_A : x_B;
    const float ag = 1.f / (1.f + expf(-(isA ? skip_A : skip_B)[0]));

    float g[8][4];
    #pragma unroll 8
    for (int r = 0; r < 8; ++r) {
        const int d = row0 + r;
        const float i0 = 1.f / (ssum[d * 2 + 0] + 1e-16f);
        const float i1 = 1.f / (ssum[d * 2 + 1] + 1e-16f);
        float a0 = 0.f, a1 = 0.f, a2 = 0.f, a3 = 0.f;
        const int beg = offsets[d], end = offsets[d + 1];
        for (int p = beg; p < end; ++p) {
            const int src = csr_src[p];
            const int ee  = csr_ee[p];
            const float c0 = alpha[(long)ee * 2 + 0] * i0;
            const float c1 = alpha[(long)ee * 2 + 1] * i1;
            const float v0 = v_src[(long)src * 128 + lane];
            const float v1 = v_src[(long)src * 128 + 64 + lane];
            const float ev = ef[(long)ee * 64 + lane];
            a0 = fmaf(c0, v0, a0);
            a1 = fmaf(c0, ev, a1);
            a2 = fmaf(c1, v1, a2);
            a3 = fmaf(c1, ev, a3);
        }
        g[r][0] = gelu_exact(a0);
        g[r][1] = gelu_exact(a1);
        g[r][2] = gelu_exact(a2);
        g[r][3] = gelu_exact(a3);
    }

    float o0[8], o1[8];
    #pragma unroll 8
    for (int r = 0; r < 8; ++r) { o0[r] = 0.f; o1[r] = 0.f; }

    #pragma unroll 4
    for (int c = 0; c < 4; ++c) {
        for (int j = 0; j < 64; ++j) {
            const int i = c * 64 + j;
            const float w0 = W[i * 128 + lane];
            const float w1 = W[i * 128 + 64 + lane];
            #pragma unroll 8
            for (int r = 0; r < 8; ++r) {
                const float s = readlanef(g[r][c], j);
                o0[r] = fmaf(s, w0, o0[r]);
                o1[r] = fmaf(s, w1, o1[r]);
            }
        }
    }

    #pragma unroll 8
    for (int r = 0; r < 8; ++r) {
        const int d = row0 + r;
        const long xb = (long)(isA ? d : d - NA) * 128;
        const float y0 = ag * (o0[r] + bo[lane])      + (1.f - ag) * xs[xb + lane];
        const float y1 = ag * (o1[r] + bo[64 + lane]) + (1.f - ag) * xs[xb + 64 + lane];
        out[(long)d * 128 + lane] = y0;
        out[(long)d * 128 + 64 + lane] = y1;
    }
}

// ---------- launcher ----------
extern "C" void kernel_launch(void* const* d_in, const int* in_sizes, int n_in,
                              void* d_out, int out_size, void* d_ws, size_t ws_size,
                              hipStream_t stream) {
    const float* x_A     = (const float*)d_in[0];
    const float* x_B     = (const float*)d_in[1];
    const float* lu_A    = (const float*)d_in[2];
    const float* lu_B    = (const float*)d_in[3];
    const float* t_AB    = (const float*)d_in[4];
    const float* t_BA    = (const float*)d_in[5];
    const float* msg_AB  = (const float*)d_in[6];
    const float* msg_BA  = (const float*)d_in[7];
    const float* W_kqv_A = (const float*)d_in[8];
    const float* b_kqv_A = (const float*)d_in[9];
    const float* W_kqv_B = (const float*)d_in[10];
    const float* b_kqv_B = (const float*)d_in[11];
    const float* Wk_rel  = (const float*)d_in[12];
    const float* Wv_rel  = (const float*)d_in[13];
    const float* W_edge  = (const float*)d_in[14];
    const float* b_edge  = (const float*)d_in[15];
    const float* W_out_A = (const float*)d_in[16];
    const float* b_out_A = (const float*)d_in[17];
    const float* W_out_B = (const float*)d_in[18];
    const float* b_out_B = (const float*)d_in[19];
    const float* skip_A  = (const float*)d_in[20];
    const float* skip_B  = (const float*)d_in[21];
    const float* p_rel_AB= (const float*)d_in[22];
    const float* p_rel_BA= (const float*)d_in[23];
    const float* time_w  = (const float*)d_in[24];
    const float* time_b  = (const float*)d_in[25];
    const int*   eiAB    = (const int*)d_in[26];
    const int*   eiBA    = (const int*)d_in[27];
    float* out = (float*)d_out;

    // workspace layout (float indices), ~325 MB total:
    //   v_src   [0      , 25.6M)
    //   q       [25.6M  , 51.2M)   dead after alpha_kernel
    //   k_src   [51.2M  , 76.8M)   dead after alpha_kernel
    //   ef      aliases q..k       [25.6M, 76.8M), written by edgefeat after expsum
    //   alpha   [76.8M  , 78.4M)
    //   m_u     [78.4M  , 78.8M)
    //   ssum    [78.8M  , 79.2M)
    //   cnt     [79.2M  , 79.4M)   (ints; becomes fill cursor)
    //   offsets [79.4M  , 79.61M)  (200001 ints, padded)
    //   csr_src [79.61M , 80.41M)
    //   csr_ee  [80.41M , 81.21M)
    float* v_src   = (float*)d_ws;
    float* q       = v_src + 25600000;
    float* k_src   = q + 25600000;
    float* ef      = q;                            // alias
    float* alpha   = k_src + 25600000;
    unsigned* m_u  = (unsigned*)(alpha + 1600000);
    float* ssum    = (float*)(m_u + 400000);
    int* cnt       = (int*)(ssum + 400000);
    int* offsets   = cnt + 200000;
    int* csr_src   = offsets + 210000;
    int* csr_ee    = csr_src + 800000;

    // zero m_u (0 == "-inf" in mapped-uint space), ssum, cnt  (contiguous 1M words)
    hipMemsetAsync(m_u, 0, (size_t)1000000 * 4, stream);

    kqv_kernel<<<(NA + KQN - 1) / KQN, 384, 0, stream>>>(x_A, W_kqv_A, b_kqv_A, Wk_rel, Wv_rel,
                                                         q, k_src, v_src, NA, 0, 0);
    kqv_kernel<<<(NB + KQN - 1) / KQN, 384, 0, stream>>>(x_B, W_kqv_B, b_kqv_B, Wk_rel, Wv_rel,
                                                         q, k_src, v_src, NB, 1, NA);
    alpha_kernel<<<8192, 256, 0, stream>>>(q, k_src, eiAB, eiBA, p_rel_AB, p_rel_BA, alpha, m_u);
    expsum_kernel<<<6400, 256, 0, stream>>>(eiAB, eiBA, alpha, m_u, ssum);
    // q, k_src dead -> ef overwrites their space
    edgefeat_kernel<<<(EE + EFN - 1) / EFN, 256, 0, stream>>>(lu_A, eiAB, t_AB, msg_AB, time_w, time_b,
                                                              W_edge, b_edge, ef, EE, 0L);
    edgefeat_kernel<<<(EE + EFN - 1) / EFN, 256, 0, stream>>>(lu_B, eiBA, t_BA, msg_BA, time_w, time_b,
                                                              W_edge, b_edge, ef, EE, (long)EE);
    count_kernel<<<(2 * EE + 255) / 256, 256, 0, stream>>>(eiAB, eiBA, cnt);
    scan_kernel<<<1, 1024, 0, stream>>>(cnt, offsets);
    fill_kernel<<<(2 * EE + 255) / 256, 256, 0, stream>>>(eiAB, eiBA, cnt, csr_src, csr_ee);
    agg_proj_kernel<<<NTOT / 32, 256, 0, stream>>>(v_src, ef, alpha, ssum, offsets, csr_src, csr_ee,
                                                   W_out_A, b_out_A, W_out_B, b_out_B,
                                                   x_A, x_B, skip_A, skip_B, out);
}

// Round 4
// 2116.887 us; speedup vs baseline: 1.1281x; 1.1211x over previous
//
#include <hip/hip_runtime.h>
#include <math.h>

#define NA 100000
#define NB 100000
#define NTOT 200000
#define EE 400000      // edges per type
#define TDIM 100       // time encoder dim

typedef short bf16x8 __attribute__((ext_vector_type(8)));
typedef float f32x4 __attribute__((ext_vector_type(4)));

// ---------- helpers ----------
__device__ __forceinline__ float gelu_exact(float x) {
    return 0.5f * x * (1.0f + erff(x * 0.70710678118654752f));
}
__device__ __forceinline__ unsigned bf16rne(float f) {
    unsigned u = __float_as_uint(f);
    return (u + 0x7fffu + ((u >> 16) & 1u)) >> 16;
}
__device__ __forceinline__ unsigned pack_bf2(float lo, float hi) {
    return bf16rne(lo) | (bf16rne(hi) << 16);
}
__device__ __forceinline__ float bf_lo(unsigned u) { return __uint_as_float(u << 16); }
__device__ __forceinline__ float bf_hi(unsigned u) { return __uint_as_float(u & 0xffff0000u); }

// ---------- K1: kqv GEMM (f32 VALU) + rel transform; outputs bf16 q + packed kv ----------
#define KQN 32
__global__ __launch_bounds__(384) void kqv_kernel(
    const float* __restrict__ x, const float* __restrict__ W, const float* __restrict__ bias,
    const float* __restrict__ Wk_rel, const float* __restrict__ Wv_rel,
    unsigned* __restrict__ q_u32, unsigned* __restrict__ kv_u32,
    int N, int et, int node_off)
{
    __shared__ float xs[KQN * 128];   // aliased as qs after GEMM
    __shared__ float ks[KQN * 128];
    __shared__ float vs[KQN * 128];
    float* qs = xs;
    const int tid = threadIdx.x;
    const int n0 = blockIdx.x * KQN;
    const int nn = min(KQN, N - n0);

    for (int i = tid; i < nn * 128; i += 384) xs[i] = x[(long)n0 * 128 + i];
    __syncthreads();

    float acc[KQN];
    {
        const int c = tid;                       // output column 0..383
        const float bc = bias[c];
        #pragma unroll
        for (int n = 0; n < KQN; ++n) acc[n] = bc;
        for (int d4 = 0; d4 < 32; ++d4) {
            const float w0 = W[(d4 * 4 + 0) * 384 + c];
            const float w1 = W[(d4 * 4 + 1) * 384 + c];
            const float w2 = W[(d4 * 4 + 2) * 384 + c];
            const float w3 = W[(d4 * 4 + 3) * 384 + c];
            #pragma unroll
            for (int n = 0; n < KQN; ++n) {
                const float4 xv = *reinterpret_cast<const float4*>(&xs[n * 128 + d4 * 4]);
                acc[n] = fmaf(xv.x, w0, fmaf(xv.y, w1, fmaf(xv.z, w2, fmaf(xv.w, w3, acc[n]))));
            }
        }
        if (c < 128) {                           // k -> LDS
            for (int n = 0; n < nn; ++n) ks[n * 128 + c] = acc[n];
        } else if (c >= 256) {                   // v -> LDS
            for (int n = 0; n < nn; ++n) vs[n * 128 + (c - 256)] = acc[n];
        }
        // q (c in [128,256)) stays in registers until xs is dead
    }
    __syncthreads();                             // ks/vs ready; xs reads done

    // q -> qs (xs alias, now dead)
    if (tid >= 128 && tid < 256) {
        const int c = tid - 128;
        for (int n = 0; n < nn; ++n) qs[n * 128 + c] = acc[n];
    }

    // rel transform (threads 0..255): k' = k @ Wk_rel[h,et], v' = v @ Wv_rel[h,et]
    float acc2[KQN];
    if (tid < 256) {
        const int grp = tid >> 7;                // 0 -> k, 1 -> v
        const int sub = tid & 127;
        const int h = sub >> 6, e2 = sub & 63;
        const float* __restrict__ Wr = (grp == 0 ? Wk_rel : Wv_rel) + (long)(h * 2 + et) * 4096;
        const float* __restrict__ sbuf = (grp == 0 ? ks : vs);
        #pragma unroll
        for (int n = 0; n < KQN; ++n) acc2[n] = 0.f;
        for (int d4 = 0; d4 < 16; ++d4) {
            const float w0 = Wr[(d4 * 4 + 0) * 64 + e2];
            const float w1 = Wr[(d4 * 4 + 1) * 64 + e2];
            const float w2 = Wr[(d4 * 4 + 2) * 64 + e2];
            const float w3 = Wr[(d4 * 4 + 3) * 64 + e2];
            #pragma unroll
            for (int n = 0; n < KQN; ++n) {
                const float4 xv = *reinterpret_cast<const float4*>(&sbuf[n * 128 + h * 64 + d4 * 4]);
                acc2[n] = fmaf(xv.x, w0, fmaf(xv.y, w1, fmaf(xv.z, w2, fmaf(xv.w, w3, acc2[n]))));
            }
        }
    }
    __syncthreads();                             // all ks/vs reads done

    if (tid < 256) {
        const int grp = tid >> 7;
        const int sub = tid & 127;
        float* dst = (grp == 0 ? ks : vs);
        for (int n = 0; n < nn; ++n) dst[n * 128 + sub] = acc2[n];
    }
    __syncthreads();                             // k', v', q all staged

    // pack q: [node][64 dwords], dword l = (q[2l], q[2l+1])
    for (int i = tid; i < nn * 64; i += 384) {
        const int n = i >> 6, l = i & 63;
        q_u32[(long)(node_off + n0 + n) * 64 + l] = pack_bf2(qs[n * 128 + 2 * l], qs[n * 128 + 2 * l + 1]);
    }
    // pack kv: [node][128 dwords], dword j: even -> (k[j],k[j+1]), odd -> (v[j-1],v[j])
    for (int i = tid; i < nn * 128; i += 384) {
        const int n = i >> 7, j = i & 127;
        unsigned val;
        if (j & 1) val = pack_bf2(vs[n * 128 + (j - 1)], vs[n * 128 + j]);
        else       val = pack_bf2(ks[n * 128 + j], ks[n * 128 + j + 1]);
        kv_u32[(long)(node_off + n0 + n) * 128 + j] = val;
    }
}

// ---------- K2: edge_feat GEMM (f32 VALU), bf16 output [2E][64] ----------
#define EFN 32
__global__ __launch_bounds__(256) void edgefeat_kernel(
    const float* __restrict__ last_update, const int* __restrict__ ei,
    const float* __restrict__ tvec, const float* __restrict__ msg,
    const float* __restrict__ time_w, const float* __restrict__ time_b,
    const float* __restrict__ W_edge, const float* __restrict__ b_edge,
    unsigned* __restrict__ ef_u32, long out_off)
{
    __shared__ float feat[EFN][164];
    __shared__ float rts[EFN];
    const int tid = threadIdx.x;
    const int lane = tid & 63;
    const int wv = tid >> 6;
    const int e0 = blockIdx.x * EFN;             // EE % 32 == 0

    if (tid < EFN) rts[tid] = last_update[ei[e0 + tid]] - tvec[e0 + tid];
    __syncthreads();
    for (int i = tid; i < EFN * TDIM; i += 256) {
        const int e = i / TDIM, j = i - e * TDIM;
        feat[e][j] = cosf(rts[e] * time_w[j] + time_b[j]);
    }
    for (int i = tid; i < EFN * 64; i += 256) {
        const int e = i >> 6, j = i & 63;
        feat[e][TDIM + j] = msg[(long)(e0 + e) * 64 + j];
    }
    __syncthreads();

    float acc[8];
    const float bc = b_edge[lane];
    #pragma unroll
    for (int k = 0; k < 8; ++k) acc[k] = bc;
    for (int t4 = 0; t4 < 41; ++t4) {
        const float w0 = W_edge[(t4 * 4 + 0) * 64 + lane];
        const float w1 = W_edge[(t4 * 4 + 1) * 64 + lane];
        const float w2 = W_edge[(t4 * 4 + 2) * 64 + lane];
        const float w3 = W_edge[(t4 * 4 + 3) * 64 + lane];
        #pragma unroll
        for (int k = 0; k < 8; ++k) {
            const float4 fv = *reinterpret_cast<const float4*>(&feat[wv * 8 + k][t4 * 4]);
            acc[k] = fmaf(fv.x, w0, fmaf(fv.y, w1, fmaf(fv.z, w2, fmaf(fv.w, w3, acc[k]))));
        }
    }
    #pragma unroll
    for (int k = 0; k < 8; ++k) {
        const float nb = __shfl_down(acc[k], 1);
        if ((lane & 1) == 0) {
            const long ee = out_off + e0 + wv * 8 + k;
            ef_u32[ee * 32 + (lane >> 1)] = pack_bf2(acc[k], nb);
        }
    }
}

// ---------- CSR build ----------
__global__ __launch_bounds__(256) void count_kernel(
    const int* __restrict__ eiAB, const int* __restrict__ eiBA, int* __restrict__ cnt)
{
    const int ee = blockIdx.x * 256 + threadIdx.x;
    if (ee >= 2 * EE) return;
    const int dst = (ee < EE) ? (eiAB[EE + ee] + NA) : eiBA[EE + (ee - EE)];
    atomicAdd(&cnt[dst], 1);
}

#define SCHUNK 196   // 1024*196 = 200704 >= NTOT
__global__ __launch_bounds__(1024) void scan_kernel(int* __restrict__ cnt, int* __restrict__ offsets)
{
    __shared__ int part[1024];
    const int t = threadIdx.x;
    const int base = t * SCHUNK;
    const int n = max(0, min(SCHUNK, NTOT - base));
    int s = 0;
    for (int i = 0; i < n; ++i) s += cnt[base + i];
    part[t] = s;
    __syncthreads();
    for (int off = 1; off < 1024; off <<= 1) {
        const int v = (t >= off) ? part[t - off] : 0;
        __syncthreads();
        part[t] += v;
        __syncthreads();
    }
    int run = part[t] - s;                 // exclusive prefix
    for (int i = 0; i < n; ++i) {
        const int c = cnt[base + i];
        offsets[base + i] = run;
        cnt[base + i] = run;               // becomes the fill cursor
        run += c;
    }
    if (t == 1023) offsets[NTOT] = part[1023];
}

__global__ __launch_bounds__(256) void fill_kernel(
    const int* __restrict__ eiAB, const int* __restrict__ eiBA,
    int* __restrict__ cursor, int* __restrict__ csr_src, int* __restrict__ csr_ee)
{
    const int ee = blockIdx.x * 256 + threadIdx.x;
    if (ee >= 2 * EE) return;
    int src, dst;
    if (ee < EE) { src = eiAB[ee];               dst = eiAB[EE + ee] + NA; }
    else { const int e = ee - EE; src = eiBA[e] + NA; dst = eiBA[EE + e]; }
    const int pos = atomicAdd(&cursor[dst], 1);
    csr_src[pos] = src;
    csr_ee[pos] = ee;
}

// ---------- K3: fused flash-softmax gather + gelu, writes g (bf16) into d_out ----------
__global__ __launch_bounds__(256) void gather_kernel(
    const unsigned* __restrict__ qb, const uint2* __restrict__ kv,
    const unsigned short* __restrict__ ef,
    const int* __restrict__ offsets, const int* __restrict__ csr_src, const int* __restrict__ csr_ee,
    const float* __restrict__ p_rel_AB, const float* __restrict__ p_rel_BA,
    unsigned short* __restrict__ g)
{
    const int lane = threadIdx.x & 63;
    const int wv = threadIdx.x >> 6;
    const int d0 = blockIdx.x * 16 + wv * 4;     // 12500 blocks, exact
    const int h = lane >> 5;
    const float sAB = p_rel_AB[h] * 0.125f;
    const float sBA = p_rel_BA[h] * 0.125f;

    for (int r = 0; r < 4; ++r) {
        const int d = d0 + r;
        const unsigned q2 = qb[(long)d * 64 + lane];
        const float ql = bf_lo(q2), qh = bf_hi(q2);
        float accv0 = 0.f, accv1 = 0.f, acce0 = 0.f, acce1 = 0.f, den = 0.f;
        const int beg = offsets[d], end = offsets[d + 1];
        for (int p = beg; p < end; ++p) {
            const int src = csr_src[p];
            const int ee = csr_ee[p];
            const uint2 kvd = kv[(long)src * 64 + lane];
            float partial = fmaf(ql, bf_lo(kvd.x), qh * bf_hi(kvd.x));
            #pragma unroll
            for (int m = 1; m <= 16; m <<= 1) partial += __shfl_xor(partial, m);
            const float s = (ee < EE) ? sAB : sBA;
            const float e = expf(partial * s);
            const float efv = __uint_as_float((unsigned)ef[(long)ee * 64 + lane] << 16);
            const float e_oth = __shfl_xor(e, 32);
            const float eh0 = (lane < 32) ? e : e_oth;
            const float eh1 = (lane < 32) ? e_oth : e;
            accv0 = fmaf(e, bf_lo(kvd.y), accv0);
            accv1 = fmaf(e, bf_hi(kvd.y), accv1);
            acce0 = fmaf(eh0, efv, acce0);
            acce1 = fmaf(eh1, efv, acce1);
            den += e;
        }
        const float inv = 1.f / (den + 1e-16f);
        const float inv_oth = __shfl_xor(inv, 32);
        const float inv0 = (lane < 32) ? inv : inv_oth;
        const float inv1 = (lane < 32) ? inv_oth : inv;
        const float gv0 = gelu_exact(accv0 * inv);
        const float gv1 = gelu_exact(accv1 * inv);
        const float ge0 = gelu_exact(acce0 * inv0);
        const float ge1 = gelu_exact(acce1 * inv1);
        unsigned short* gp = g + (long)d * 256;
        *reinterpret_cast<unsigned*>(gp + 2 * lane + ((lane < 32) ? 0 : 64)) = pack_bf2(gv0, gv1);
        gp[64 + lane] = (unsigned short)bf16rne(ge0);
        gp[192 + lane] = (unsigned short)bf16rne(ge1);
    }
}

// ---------- K4: MFMA out-projection: out = skip-gate( g @ W_out + b ), in-place over g ----------
__global__ __launch_bounds__(256) void proj_mfma_kernel(
    const short* __restrict__ g,          // bf16 rows of 256, node-indexed (== d_out bytes)
    const float* __restrict__ W_out, const float* __restrict__ b_out,
    const float* __restrict__ x, const float* __restrict__ skip,
    float* __restrict__ out, int roff, int N)
{
    __shared__ unsigned short Wt[128 * 264];     // W^T bf16, padded rows (264)
    const int tid = threadIdx.x;
    const int lane = tid & 63;
    const int wv = tid >> 6;

    for (int idx = tid; idx < 256 * 128; idx += 256) {
        const int k = idx >> 7, n = idx & 127;
        Wt[n * 264 + k] = (unsigned short)bf16rne(W_out[idx]);
    }
    __syncthreads();

    const int m0 = roff + blockIdx.x * 64 + wv * 16;   // this wave's 16 rows
    const int rmax = roff + N - 1;
    const float ag = 1.f / (1.f + expf(-skip[0]));

    f32x4 acc[8];
    #pragma unroll
    for (int nf = 0; nf < 8; ++nf) acc[nf] = (f32x4){0.f, 0.f, 0.f, 0.f};

    const int arow = min(m0 + (lane & 15), rmax);
    const int kgrp = (lane >> 4) * 8;

    #pragma unroll
    for (int ks = 0; ks < 8; ++ks) {
        const bf16x8 a = *reinterpret_cast<const bf16x8*>(g + (long)arow * 256 + ks * 32 + kgrp);
        #pragma unroll
        for (int nf = 0; nf < 8; ++nf) {
            const bf16x8 b = *reinterpret_cast<const bf16x8*>(&Wt[(nf * 16 + (lane & 15)) * 264 + ks * 32 + kgrp]);
            acc[nf] = __builtin_amdgcn_mfma_f32_16x16x32_bf16(a, b, acc[nf], 0, 0, 0);
        }
    }

    #pragma unroll
    for (int nf = 0; nf < 8; ++nf) {
        const int col = nf * 16 + (lane & 15);
        const float bc = b_out[col];
        #pragma unroll
        for (int reg = 0; reg < 4; ++reg) {
            const int d = m0 + (lane >> 4) * 4 + reg;
            if (d <= rmax) {
                const float xv = x[(long)(d - roff) * 128 + col];
                out[(long)d * 128 + col] = fmaf(ag, acc[nf][reg] + bc, (1.f - ag) * xv);
            }
        }
    }
}

// ---------- launcher ----------
extern "C" void kernel_launch(void* const* d_in, const int* in_sizes, int n_in,
                              void* d_out, int out_size, void* d_ws, size_t ws_size,
                              hipStream_t stream) {
    const float* x_A     = (const float*)d_in[0];
    const float* x_B     = (const float*)d_in[1];
    const float* lu_A    = (const float*)d_in[2];
    const float* lu_B    = (const float*)d_in[3];
    const float* t_AB    = (const float*)d_in[4];
    const float* t_BA    = (const float*)d_in[5];
    const float* msg_AB  = (const float*)d_in[6];
    const float* msg_BA  = (const float*)d_in[7];
    const float* W_kqv_A = (const float*)d_in[8];
    const float* b_kqv_A = (const float*)d_in[9];
    const float* W_kqv_B = (const float*)d_in[10];
    const float* b_kqv_B = (const float*)d_in[11];
    const float* Wk_rel  = (const float*)d_in[12];
    const float* Wv_rel  = (const float*)d_in[13];
    const float* W_edge  = (const float*)d_in[14];
    const float* b_edge  = (const float*)d_in[15];
    const float* W_out_A = (const float*)d_in[16];
    const float* b_out_A = (const float*)d_in[17];
    const float* W_out_B = (const float*)d_in[18];
    const float* b_out_B = (const float*)d_in[19];
    const float* skip_A  = (const float*)d_in[20];
    const float* skip_B  = (const float*)d_in[21];
    const float* p_rel_AB= (const float*)d_in[22];
    const float* p_rel_BA= (const float*)d_in[23];
    const float* time_w  = (const float*)d_in[24];
    const float* time_b  = (const float*)d_in[25];
    const int*   eiAB    = (const int*)d_in[26];
    const int*   eiBA    = (const int*)d_in[27];
    float* out = (float*)d_out;

    // workspace layout (~264 MB):
    //   q_bf  [node][64 u32]   51.2 MB
    //   kv    [node][64 uint2] 102.4 MB
    //   ef    [2E][32 u32]     102.4 MB
    //   cnt[200000] offsets[200001..pad] csr_src[800000] csr_ee[800000]  ~8 MB
    // g (bf16, [node][256]) lives IN d_out; proj overwrites it in place.
    unsigned* q_bf  = (unsigned*)d_ws;
    uint2*    kvbuf = (uint2*)(q_bf + 12800000);
    unsigned* efbuf = (unsigned*)(kvbuf + 12800000);
    int* cnt      = (int*)(efbuf + 25600000);
    int* offsets  = cnt + 200000;
    int* csr_src  = offsets + 210000;
    int* csr_ee   = csr_src + 800000;

    hipMemsetAsync(cnt, 0, (size_t)200000 * 4, stream);

    count_kernel<<<(2 * EE + 255) / 256, 256, 0, stream>>>(eiAB, eiBA, cnt);
    scan_kernel<<<1, 1024, 0, stream>>>(cnt, offsets);
    fill_kernel<<<(2 * EE + 255) / 256, 256, 0, stream>>>(eiAB, eiBA, cnt, csr_src, csr_ee);

    kqv_kernel<<<NA / KQN, 384, 0, stream>>>(x_A, W_kqv_A, b_kqv_A, Wk_rel, Wv_rel,
                                             q_bf, (unsigned*)kvbuf, NA, 0, 0);
    kqv_kernel<<<NB / KQN, 384, 0, stream>>>(x_B, W_kqv_B, b_kqv_B, Wk_rel, Wv_rel,
                                             q_bf, (unsigned*)kvbuf, NB, 1, NA);
    edgefeat_kernel<<<EE / EFN, 256, 0, stream>>>(lu_A, eiAB, t_AB, msg_AB, time_w, time_b,
                                                  W_edge, b_edge, efbuf, 0L);
    edgefeat_kernel<<<EE / EFN, 256, 0, stream>>>(lu_B, eiBA, t_BA, msg_BA, time_w, time_b,
                                                  W_edge, b_edge, efbuf, (long)EE);

    gather_kernel<<<NTOT / 16, 256, 0, stream>>>(q_bf, kvbuf, (const unsigned short*)efbuf,
                                                 offsets, csr_src, csr_ee,
                                                 p_rel_AB, p_rel_BA, (unsigned short*)out);

    proj_mfma_kernel<<<(NA + 63) / 64, 256, 0, stream>>>((const short*)out, W_out_A, b_out_A,
                                                         x_A, skip_A, out, 0, NA);
    proj_mfma_kernel<<<(NB + 63) / 64, 256, 0, stream>>>((const short*)out, W_out_B, b_out_B,
                                                         x_B, skip_B, out, NA, NB);
}

// Round 6
// 1087.653 us; speedup vs baseline: 2.1956x; 1.9463x over previous
//
#include <hip/hip_runtime.h>
#include <math.h>

#define NA 100000
#define NB 100000
#define NTOT 200000
#define EE 400000      // edges per type
#define TDIM 100       // time encoder dim

typedef short bf16x8 __attribute__((ext_vector_type(8)));
typedef float f32x4 __attribute__((ext_vector_type(4)));

// ---------- helpers ----------
__device__ __forceinline__ float gelu_exact(float x) {
    return 0.5f * x * (1.0f + erff(x * 0.70710678118654752f));
}
__device__ __forceinline__ unsigned bf16rne(float f) {
    unsigned u = __float_as_uint(f);
    return (u + 0x7fffu + ((u >> 16) & 1u)) >> 16;
}
__device__ __forceinline__ unsigned pack_bf2(float lo, float hi) {
    return bf16rne(lo) | (bf16rne(hi) << 16);
}
__device__ __forceinline__ float bf_lo(unsigned u) { return __uint_as_float(u << 16); }
__device__ __forceinline__ float bf_hi(unsigned u) { return __uint_as_float(u & 0xffff0000u); }

// ---------- K0: fuse rel-transform into kqv weights ----------
// Wf_t[c][i] (bf16, [384][128]): c<128 -> k' cols, 128..255 -> q, 256..383 -> v'
__global__ __launch_bounds__(128) void fusew_kernel(
    const float* __restrict__ W, const float* __restrict__ b,
    const float* __restrict__ Wk_rel, const float* __restrict__ Wv_rel,
    int et, unsigned short* __restrict__ Wf_t, float* __restrict__ bf)
{
    const int c = blockIdx.x;        // 0..383
    const int i = threadIdx.x;       // 0..127
    float acc = 0.f;
    if (c < 128) {
        const int h = c >> 6, e = c & 63;
        const float* __restrict__ Wr = Wk_rel + (long)(h * 2 + et) * 4096;
        for (int d = 0; d < 64; ++d) acc += W[i * 384 + h * 64 + d] * Wr[d * 64 + e];
    } else if (c < 256) {
        acc = W[i * 384 + c];
    } else {
        const int h = (c - 256) >> 6, e = (c - 256) & 63;
        const float* __restrict__ Wr = Wv_rel + (long)(h * 2 + et) * 4096;
        for (int d = 0; d < 64; ++d) acc += W[i * 384 + 256 + h * 64 + d] * Wr[d * 64 + e];
    }
    Wf_t[c * 128 + i] = (unsigned short)bf16rne(acc);
    if (i == 0) {
        float bacc = 0.f;
        if (c < 128) {
            const int h = c >> 6, e = c & 63;
            const float* __restrict__ Wr = Wk_rel + (long)(h * 2 + et) * 4096;
            for (int d = 0; d < 64; ++d) bacc += b[h * 64 + d] * Wr[d * 64 + e];
        } else if (c < 256) {
            bacc = b[c];
        } else {
            const int h = (c - 256) >> 6, e = (c - 256) & 63;
            const float* __restrict__ Wr = Wv_rel + (long)(h * 2 + et) * 4096;
            for (int d = 0; d < 64; ++d) bacc += b[256 + h * 64 + d] * Wr[d * 64 + e];
        }
        bf[c] = bacc;
    }
}

// ---------- K1: kqv MFMA GEMM: [q|k'|v'] = x @ Wf + bf, packed bf16 outputs ----------
#define BM 64
__global__ __launch_bounds__(256) void kqv_mfma_kernel(
    const float* __restrict__ x, const unsigned short* __restrict__ Wf_t,
    const float* __restrict__ bf,
    unsigned* __restrict__ q_u32, unsigned* __restrict__ kv_u32,
    int N, int node_off)
{
    __shared__ unsigned xs[BM][68];              // pair-packed bf16, +4 dword pad
    const int tid = threadIdx.x;
    const int lane = tid & 63;
    const int wv = tid >> 6;
    const int kq = lane >> 4;                    // k-group 0..3
    const int n0 = blockIdx.x * BM;

    for (int idx = tid; idx < BM * 64; idx += 256) {
        const int n = idx >> 6, j = idx & 63;
        unsigned p = 0;
        const int node = n0 + n;
        if (node < N) {
            const float2 xv = *reinterpret_cast<const float2*>(x + (long)node * 128 + 2 * j);
            p = pack_bf2(xv.x, xv.y);
        }
        xs[n][j] = p;
    }
    __syncthreads();

    const int wq = wv * 96;                      // this wave's col base
    f32x4 acc[4][6];
    #pragma unroll
    for (int mt = 0; mt < 4; ++mt)
        #pragma unroll
        for (int nt = 0; nt < 6; ++nt) acc[mt][nt] = (f32x4){0.f, 0.f, 0.f, 0.f};

    #pragma unroll
    for (int ks = 0; ks < 4; ++ks) {
        bf16x8 a[4], bfr[6];
        #pragma unroll
        for (int mt = 0; mt < 4; ++mt)
            a[mt] = *reinterpret_cast<const bf16x8*>(&xs[mt * 16 + (lane & 15)][ks * 16 + kq * 4]);
        #pragma unroll
        for (int nt = 0; nt < 6; ++nt) {
            const int col = wq + nt * 16 + (lane & 15);
            bfr[nt] = *reinterpret_cast<const bf16x8*>(Wf_t + (long)col * 128 + ks * 32 + kq * 8);
        }
        #pragma unroll
        for (int mt = 0; mt < 4; ++mt)
            #pragma unroll
            for (int nt = 0; nt < 6; ++nt)
                acc[mt][nt] = __builtin_amdgcn_mfma_f32_16x16x32_bf16(a[mt], bfr[nt], acc[mt][nt], 0, 0, 0);
    }

    // epilogue: +bias, pair-exchange with lane^1, even lanes store packed u32
    #pragma unroll
    for (int nt = 0; nt < 6; ++nt) {
        const int c = wq + nt * 16 + (lane & 15);
        const float bias_c = bf[c];
        #pragma unroll
        for (int mt = 0; mt < 4; ++mt) {
            #pragma unroll
            for (int reg = 0; reg < 4; ++reg) {
                const int node = n0 + mt * 16 + kq * 4 + reg;
                const float v = acc[mt][nt][reg] + bias_c;
                const float o = __shfl_xor(v, 1);
                if (!(lane & 1) && node < N) {
                    const unsigned p = pack_bf2(v, o);
                    const long nb = node_off + node;
                    if (c < 128)      kv_u32[nb * 128 + c] = p;             // k-pair at even dword c
                    else if (c < 256) q_u32[nb * 64 + ((c - 128) >> 1)] = p;
                    else              kv_u32[nb * 128 + (c - 256) + 1] = p; // v-pair at odd dword
                }
            }
        }
    }
}

// ---------- K2: edge_feat GEMM (f32 VALU), bf16 output [2E][64] ----------
#define EFN 32
__global__ __launch_bounds__(256) void edgefeat_kernel(
    const float* __restrict__ last_update, const int* __restrict__ ei,
    const float* __restrict__ tvec, const float* __restrict__ msg,
    const float* __restrict__ time_w, const float* __restrict__ time_b,
    const float* __restrict__ W_edge, const float* __restrict__ b_edge,
    unsigned* __restrict__ ef_u32, long out_off)
{
    __shared__ float feat[EFN][164];
    __shared__ float rts[EFN];
    const int tid = threadIdx.x;
    const int lane = tid & 63;
    const int wv = tid >> 6;
    const int e0 = blockIdx.x * EFN;             // EE % 32 == 0

    if (tid < EFN) rts[tid] = last_update[ei[e0 + tid]] - tvec[e0 + tid];
    __syncthreads();
    for (int i = tid; i < EFN * TDIM; i += 256) {
        const int e = i / TDIM, j = i - e * TDIM;
        feat[e][j] = cosf(rts[e] * time_w[j] + time_b[j]);
    }
    for (int i = tid; i < EFN * 64; i += 256) {
        const int e = i >> 6, j = i & 63;
        feat[e][TDIM + j] = msg[(long)(e0 + e) * 64 + j];
    }
    __syncthreads();

    float acc[8];
    const float bc = b_edge[lane];
    #pragma unroll
    for (int k = 0; k < 8; ++k) acc[k] = bc;
    for (int t4 = 0; t4 < 41; ++t4) {
        const float w0 = W_edge[(t4 * 4 + 0) * 64 + lane];
        const float w1 = W_edge[(t4 * 4 + 1) * 64 + lane];
        const float w2 = W_edge[(t4 * 4 + 2) * 64 + lane];
        const float w3 = W_edge[(t4 * 4 + 3) * 64 + lane];
        #pragma unroll
        for (int k = 0; k < 8; ++k) {
            const float4 fv = *reinterpret_cast<const float4*>(&feat[wv * 8 + k][t4 * 4]);
            acc[k] = fmaf(fv.x, w0, fmaf(fv.y, w1, fmaf(fv.z, w2, fmaf(fv.w, w3, acc[k]))));
        }
    }
    #pragma unroll
    for (int k = 0; k < 8; ++k) {
        const float nb = __shfl_down(acc[k], 1);
        if ((lane & 1) == 0) {
            const long ee = out_off + e0 + wv * 8 + k;
            ef_u32[ee * 32 + (lane >> 1)] = pack_bf2(acc[k], nb);
        }
    }
}

// ---------- CSR build ----------
__global__ __launch_bounds__(256) void count_kernel(
    const int* __restrict__ eiAB, const int* __restrict__ eiBA, int* __restrict__ cnt)
{
    const int ee = blockIdx.x * 256 + threadIdx.x;
    if (ee >= 2 * EE) return;
    const int dst = (ee < EE) ? (eiAB[EE + ee] + NA) : eiBA[EE + (ee - EE)];
    atomicAdd(&cnt[dst], 1);
}

// 3-stage parallel exclusive scan over cnt[NTOT] -> offsets, + cursor init
__global__ __launch_bounds__(1024) void scan1_kernel(
    const int* __restrict__ cnt, int* __restrict__ offsets, int* __restrict__ bsum)
{
    __shared__ int tmp[1024];
    const int t = threadIdx.x;
    const int i = blockIdx.x * 1024 + t;
    const int v = (i < NTOT) ? cnt[i] : 0;
    tmp[t] = v;
    __syncthreads();
    for (int off = 1; off < 1024; off <<= 1) {
        const int u = (t >= off) ? tmp[t - off] : 0;
        __syncthreads();
        tmp[t] += u;
        __syncthreads();
    }
    offsets[i] = tmp[t] - v;           // local exclusive prefix
    if (t == 1023) bsum[blockIdx.x] = tmp[1023];
}

__global__ __launch_bounds__(256) void scan2_kernel(
    const int* __restrict__ bsum, int* __restrict__ bbase, int nblk)
{
    __shared__ int tmp[256];
    const int t = threadIdx.x;
    const int v = (t < nblk) ? bsum[t] : 0;
    tmp[t] = v;
    __syncthreads();
    for (int off = 1; off < 256; off <<= 1) {
        const int u = (t >= off) ? tmp[t - off] : 0;
        __syncthreads();
        tmp[t] += u;
        __syncthreads();
    }
    bbase[t] = tmp[t] - v;             // exclusive
}

__global__ __launch_bounds__(1024) void scan3_kernel(
    int* __restrict__ offsets, const int* __restrict__ bbase, int* __restrict__ cnt)
{
    const int t = threadIdx.x;
    const int i = blockIdx.x * 1024 + t;
    const int o = offsets[i] + bbase[blockIdx.x];
    offsets[i] = o;
    if (i < NTOT) cnt[i] = o;          // fill cursor
    if (blockIdx.x == 0 && t == 0) offsets[NTOT] = 2 * EE;
}

__global__ __launch_bounds__(256) void fill_kernel(
    const int* __restrict__ eiAB, const int* __restrict__ eiBA,
    int* __restrict__ cursor, int* __restrict__ csr_src, int* __restrict__ csr_ee)
{
    const int ee = blockIdx.x * 256 + threadIdx.x;
    if (ee >= 2 * EE) return;
    int src, dst;
    if (ee < EE) { src = eiAB[ee];               dst = eiAB[EE + ee] + NA; }
    else { const int e = ee - EE; src = eiBA[e] + NA; dst = eiBA[EE + e]; }
    const int pos = atomicAdd(&cursor[dst], 1);
    csr_src[pos] = src;
    csr_ee[pos] = ee;
}

// ---------- K3: fused flash-softmax gather + gelu, writes g (bf16) into d_out ----------
__global__ __launch_bounds__(256) void gather_kernel(
    const unsigned* __restrict__ qb, const uint2* __restrict__ kv,
    const unsigned short* __restrict__ ef,
    const int* __restrict__ offsets, const int* __restrict__ csr_src, const int* __restrict__ csr_ee,
    const float* __restrict__ p_rel_AB, const float* __restrict__ p_rel_BA,
    unsigned short* __restrict__ g)
{
    const int lane = threadIdx.x & 63;
    const int wv = threadIdx.x >> 6;
    const int d0 = blockIdx.x * 16 + wv * 4;     // 12500 blocks, exact
    const int h = lane >> 5;
    const float sAB = p_rel_AB[h] * 0.125f;
    const float sBA = p_rel_BA[h] * 0.125f;

    for (int r = 0; r < 4; ++r) {
        const int d = d0 + r;
        const unsigned q2 = qb[(long)d * 64 + lane];
        const float ql = bf_lo(q2), qh = bf_hi(q2);
        float accv0 = 0.f, accv1 = 0.f, acce0 = 0.f, acce1 = 0.f, den = 0.f;
        const int beg = offsets[d], end = offsets[d + 1];
        for (int p = beg; p < end; ++p) {
            const int src = csr_src[p];
            const int ee = csr_ee[p];
            const uint2 kvd = kv[(long)src * 64 + lane];
            float partial = fmaf(ql, bf_lo(kvd.x), qh * bf_hi(kvd.x));
            #pragma unroll
            for (int m = 1; m <= 16; m <<= 1) partial += __shfl_xor(partial, m);
            const float s = (ee < EE) ? sAB : sBA;
            const float e = expf(partial * s);
            const float efv = __uint_as_float((unsigned)ef[(long)ee * 64 + lane] << 16);
            const float e_oth = __shfl_xor(e, 32);
            const float eh0 = (lane < 32) ? e : e_oth;
            const float eh1 = (lane < 32) ? e_oth : e;
            accv0 = fmaf(e, bf_lo(kvd.y), accv0);
            accv1 = fmaf(e, bf_hi(kvd.y), accv1);
            acce0 = fmaf(eh0, efv, acce0);
            acce1 = fmaf(eh1, efv, acce1);
            den += e;
        }
        const float inv = 1.f / (den + 1e-16f);
        const float inv_oth = __shfl_xor(inv, 32);
        const float inv0 = (lane < 32) ? inv : inv_oth;
        const float inv1 = (lane < 32) ? inv_oth : inv;
        const float gv0 = gelu_exact(accv0 * inv);
        const float gv1 = gelu_exact(accv1 * inv);
        const float ge0 = gelu_exact(acce0 * inv0);
        const float ge1 = gelu_exact(acce1 * inv1);
        unsigned short* gp = g + (long)d * 256;
        *reinterpret_cast<unsigned*>(gp + 2 * lane + ((lane < 32) ? 0 : 64)) = pack_bf2(gv0, gv1);
        gp[64 + lane] = (unsigned short)bf16rne(ge0);
        gp[192 + lane] = (unsigned short)bf16rne(ge1);
    }
}

// ---------- K4: MFMA out-projection: out = skip-gate( g @ W_out + b ), in-place over g ----------
__global__ __launch_bounds__(256) void proj_mfma_kernel(
    const short* __restrict__ g,          // bf16 rows of 256, node-indexed (== d_out bytes)
    const float* __restrict__ W_out, const float* __restrict__ b_out,
    const float* __restrict__ x, const float* __restrict__ skip,
    float* __restrict__ out, int roff, int N)
{
    __shared__ unsigned short Wt[128 * 264];     // W^T bf16, padded rows (264)
    const int tid = threadIdx.x;
    const int lane = tid & 63;
    const int wv = tid >> 6;

    for (int idx = tid; idx < 256 * 128; idx += 256) {
        const int k = idx >> 7, n = idx & 127;
        Wt[n * 264 + k] = (unsigned short)bf16rne(W_out[idx]);
    }
    __syncthreads();

    const int m0 = roff + blockIdx.x * 64 + wv * 16;   // this wave's 16 rows
    const int rmax = roff + N - 1;
    const float ag = 1.f / (1.f + expf(-skip[0]));

    f32x4 acc[8];
    #pragma unroll
    for (int nf = 0; nf < 8; ++nf) acc[nf] = (f32x4){0.f, 0.f, 0.f, 0.f};

    const int arow = min(m0 + (lane & 15), rmax);
    const int kgrp = (lane >> 4) * 8;

    #pragma unroll
    for (int ks = 0; ks < 8; ++ks) {
        const bf16x8 a = *reinterpret_cast<const bf16x8*>(g + (long)arow * 256 + ks * 32 + kgrp);
        #pragma unroll
        for (int nf = 0; nf < 8; ++nf) {
            const bf16x8 b = *reinterpret_cast<const bf16x8*>(&Wt[(nf * 16 + (lane & 15)) * 264 + ks * 32 + kgrp]);
            acc[nf] = __builtin_amdgcn_mfma_f32_16x16x32_bf16(a, b, acc[nf], 0, 0, 0);
        }
    }

    #pragma unroll
    for (int nf = 0; nf < 8; ++nf) {
        const int col = nf * 16 + (lane & 15);
        const float bc = b_out[col];
        #pragma unroll
        for (int reg = 0; reg < 4; ++reg) {
            const int d = m0 + (lane >> 4) * 4 + reg;
            if (d <= rmax) {
                const float xv = x[(long)(d - roff) * 128 + col];
                out[(long)d * 128 + col] = fmaf(ag, acc[nf][reg] + bc, (1.f - ag) * xv);
            }
        }
    }
}

// ---------- launcher ----------
extern "C" void kernel_launch(void* const* d_in, const int* in_sizes, int n_in,
                              void* d_out, int out_size, void* d_ws, size_t ws_size,
                              hipStream_t stream) {
    const float* x_A     = (const float*)d_in[0];
    const float* x_B     = (const float*)d_in[1];
    const float* lu_A    = (const float*)d_in[2];
    const float* lu_B    = (const float*)d_in[3];
    const float* t_AB    = (const float*)d_in[4];
    const float* t_BA    = (const float*)d_in[5];
    const float* msg_AB  = (const float*)d_in[6];
    const float* msg_BA  = (const float*)d_in[7];
    const float* W_kqv_A = (const float*)d_in[8];
    const float* b_kqv_A = (const float*)d_in[9];
    const float* W_kqv_B = (const float*)d_in[10];
    const float* b_kqv_B = (const float*)d_in[11];
    const float* Wk_rel  = (const float*)d_in[12];
    const float* Wv_rel  = (const float*)d_in[13];
    const float* W_edge  = (const float*)d_in[14];
    const float* b_edge  = (const float*)d_in[15];
    const float* W_out_A = (const float*)d_in[16];
    const float* b_out_A = (const float*)d_in[17];
    const float* W_out_B = (const float*)d_in[18];
    const float* b_out_B = (const float*)d_in[19];
    const float* skip_A  = (const float*)d_in[20];
    const float* skip_B  = (const float*)d_in[21];
    const float* p_rel_AB= (const float*)d_in[22];
    const float* p_rel_BA= (const float*)d_in[23];
    const float* time_w  = (const float*)d_in[24];
    const float* time_b  = (const float*)d_in[25];
    const int*   eiAB    = (const int*)d_in[26];
    const int*   eiBA    = (const int*)d_in[27];
    float* out = (float*)d_out;

    // workspace layout (~264 MB)
    unsigned* q_bf  = (unsigned*)d_ws;                  // 12.8M u32
    unsigned* kvbuf = q_bf + 12800000;                  // 25.6M u32
    unsigned* efbuf = kvbuf + 25600000;                 // 25.6M u32
    int* cnt      = (int*)(efbuf + 25600000);           // 200000
    int* offsets  = cnt + 200000;                       // 210000 (196*1024=200704 used)
    int* csr_src  = offsets + 210000;                   // 800000
    int* csr_ee   = csr_src + 800000;                   // 800000
    unsigned short* WfA = (unsigned short*)(csr_ee + 800000);  // 49152 bf16
    unsigned short* WfB = WfA + 49152;                  // 49152 bf16
    float* bfA    = (float*)(WfB + 49152);              // 384
    float* bfB    = bfA + 384;                          // 384
    int* bsum     = (int*)(bfB + 384);                  // 256
    int* bbase    = bsum + 256;                         // 256

    (void)hipMemsetAsync(cnt, 0, (size_t)200000 * 4, stream);

    // CSR build
    count_kernel<<<(2 * EE + 255) / 256, 256, 0, stream>>>(eiAB, eiBA, cnt);
    scan1_kernel<<<196, 1024, 0, stream>>>(cnt, offsets, bsum);
    scan2_kernel<<<1, 256, 0, stream>>>(bsum, bbase, 196);
    scan3_kernel<<<196, 1024, 0, stream>>>(offsets, bbase, cnt);
    fill_kernel<<<(2 * EE + 255) / 256, 256, 0, stream>>>(eiAB, eiBA, cnt, csr_src, csr_ee);

    // fused kqv weights + MFMA kqv
    fusew_kernel<<<384, 128, 0, stream>>>(W_kqv_A, b_kqv_A, Wk_rel, Wv_rel, 0, WfA, bfA);
    fusew_kernel<<<384, 128, 0, stream>>>(W_kqv_B, b_kqv_B, Wk_rel, Wv_rel, 1, WfB, bfB);
    kqv_mfma_kernel<<<(NA + BM - 1) / BM, 256, 0, stream>>>(x_A, WfA, bfA, q_bf, kvbuf, NA, 0);
    kqv_mfma_kernel<<<(NB + BM - 1) / BM, 256, 0, stream>>>(x_B, WfB, bfB, q_bf, kvbuf, NB, NA);

    edgefeat_kernel<<<EE / EFN, 256, 0, stream>>>(lu_A, eiAB, t_AB, msg_AB, time_w, time_b,
                                                  W_edge, b_edge, efbuf, 0L);
    edgefeat_kernel<<<EE / EFN, 256, 0, stream>>>(lu_B, eiBA, t_BA, msg_BA, time_w, time_b,
                                                  W_edge, b_edge, efbuf, (long)EE);

    gather_kernel<<<NTOT / 16, 256, 0, stream>>>(q_bf, (const uint2*)kvbuf,
                                                 (const unsigned short*)efbuf,
                                                 offsets, csr_src, csr_ee,
                                                 p_rel_AB, p_rel_BA, (unsigned short*)out);

    proj_mfma_kernel<<<(NA + 63) / 64, 256, 0, stream>>>((const short*)out, W_out_A, b_out_A,
                                                         x_A, skip_A, out, 0, NA);
    proj_mfma_kernel<<<(NB + 63) / 64, 256, 0, stream>>>((const short*)out, W_out_B, b_out_B,
                                                         x_B, skip_B, out, NA, NB);
}

// Round 7
// 929.928 us; speedup vs baseline: 2.5681x; 1.1696x over previous
//
#include <hip/hip_runtime.h>
#include <math.h>

#define NA 100000
#define NB 100000
#define NTOT 200000
#define EE 400000      // edges per type
#define TDIM 100       // time encoder dim

typedef short bf16x8 __attribute__((ext_vector_type(8)));
typedef float f32x4 __attribute__((ext_vector_type(4)));

// ---------- helpers ----------
__device__ __forceinline__ float gelu_exact(float x) {
    return 0.5f * x * (1.0f + erff(x * 0.70710678118654752f));
}
__device__ __forceinline__ unsigned bf16rne(float f) {
    unsigned u = __float_as_uint(f);
    return (u + 0x7fffu + ((u >> 16) & 1u)) >> 16;
}
__device__ __forceinline__ unsigned pack_bf2(float lo, float hi) {
    return bf16rne(lo) | (bf16rne(hi) << 16);
}
__device__ __forceinline__ float bf_lo(unsigned u) { return __uint_as_float(u << 16); }
__device__ __forceinline__ float bf_hi(unsigned u) { return __uint_as_float(u & 0xffff0000u); }

// ---------- K0: fuse rel-transform into kqv weights ----------
__global__ __launch_bounds__(128) void fusew_kernel(
    const float* __restrict__ W, const float* __restrict__ b,
    const float* __restrict__ Wk_rel, const float* __restrict__ Wv_rel,
    int et, unsigned short* __restrict__ Wf_t, float* __restrict__ bf)
{
    const int c = blockIdx.x;        // 0..383
    const int i = threadIdx.x;       // 0..127
    float acc = 0.f;
    if (c < 128) {
        const int h = c >> 6, e = c & 63;
        const float* __restrict__ Wr = Wk_rel + (long)(h * 2 + et) * 4096;
        for (int d = 0; d < 64; ++d) acc += W[i * 384 + h * 64 + d] * Wr[d * 64 + e];
    } else if (c < 256) {
        acc = W[i * 384 + c];
    } else {
        const int h = (c - 256) >> 6, e = (c - 256) & 63;
        const float* __restrict__ Wr = Wv_rel + (long)(h * 2 + et) * 4096;
        for (int d = 0; d < 64; ++d) acc += W[i * 384 + 256 + h * 64 + d] * Wr[d * 64 + e];
    }
    Wf_t[c * 128 + i] = (unsigned short)bf16rne(acc);
    if (i == 0) {
        float bacc = 0.f;
        if (c < 128) {
            const int h = c >> 6, e = c & 63;
            const float* __restrict__ Wr = Wk_rel + (long)(h * 2 + et) * 4096;
            for (int d = 0; d < 64; ++d) bacc += b[h * 64 + d] * Wr[d * 64 + e];
        } else if (c < 256) {
            bacc = b[c];
        } else {
            const int h = (c - 256) >> 6, e = (c - 256) & 63;
            const float* __restrict__ Wr = Wv_rel + (long)(h * 2 + et) * 4096;
            for (int d = 0; d < 64; ++d) bacc += b[256 + h * 64 + d] * Wr[d * 64 + e];
        }
        bf[c] = bacc;
    }
}

// ---------- K0b: W_edge^T -> bf16 [64][192] (k padded 164->192) ----------
__global__ __launch_bounds__(192) void wedget_kernel(
    const float* __restrict__ W_edge, unsigned short* __restrict__ Wt)
{
    const int col = blockIdx.x;      // 0..63
    const int k = threadIdx.x;       // 0..191
    const float v = (k < 164) ? W_edge[k * 64 + col] : 0.f;
    Wt[col * 192 + k] = (unsigned short)bf16rne(v);
}

// ---------- K1: kqv MFMA GEMM: [q|k'|v'] = x @ Wf + bf, packed bf16 outputs ----------
#define BM 64
__global__ __launch_bounds__(256) void kqv_mfma_kernel(
    const float* __restrict__ x, const unsigned short* __restrict__ Wf_t,
    const float* __restrict__ bf,
    unsigned* __restrict__ q_u32, unsigned* __restrict__ kv_u32,
    int N, int node_off)
{
    __shared__ unsigned xs[BM][68];              // pair-packed bf16, +4 dword pad
    const int tid = threadIdx.x;
    const int lane = tid & 63;
    const int wv = tid >> 6;
    const int kq = lane >> 4;                    // k-group 0..3
    const int n0 = blockIdx.x * BM;

    for (int idx = tid; idx < BM * 64; idx += 256) {
        const int n = idx >> 6, j = idx & 63;
        unsigned p = 0;
        const int node = n0 + n;
        if (node < N) {
            const float2 xv = *reinterpret_cast<const float2*>(x + (long)node * 128 + 2 * j);
            p = pack_bf2(xv.x, xv.y);
        }
        xs[n][j] = p;
    }
    __syncthreads();

    const int wq = wv * 96;                      // this wave's col base
    f32x4 acc[4][6];
    #pragma unroll
    for (int mt = 0; mt < 4; ++mt)
        #pragma unroll
        for (int nt = 0; nt < 6; ++nt) acc[mt][nt] = (f32x4){0.f, 0.f, 0.f, 0.f};

    #pragma unroll
    for (int ks = 0; ks < 4; ++ks) {
        bf16x8 a[4], bfr[6];
        #pragma unroll
        for (int mt = 0; mt < 4; ++mt)
            a[mt] = *reinterpret_cast<const bf16x8*>(&xs[mt * 16 + (lane & 15)][ks * 16 + kq * 4]);
        #pragma unroll
        for (int nt = 0; nt < 6; ++nt) {
            const int col = wq + nt * 16 + (lane & 15);
            bfr[nt] = *reinterpret_cast<const bf16x8*>(Wf_t + (long)col * 128 + ks * 32 + kq * 8);
        }
        #pragma unroll
        for (int mt = 0; mt < 4; ++mt)
            #pragma unroll
            for (int nt = 0; nt < 6; ++nt)
                acc[mt][nt] = __builtin_amdgcn_mfma_f32_16x16x32_bf16(a[mt], bfr[nt], acc[mt][nt], 0, 0, 0);
    }

    #pragma unroll
    for (int nt = 0; nt < 6; ++nt) {
        const int c = wq + nt * 16 + (lane & 15);
        const float bias_c = bf[c];
        #pragma unroll
        for (int mt = 0; mt < 4; ++mt) {
            #pragma unroll
            for (int reg = 0; reg < 4; ++reg) {
                const int node = n0 + mt * 16 + kq * 4 + reg;
                const float v = acc[mt][nt][reg] + bias_c;
                const float o = __shfl_xor(v, 1);
                if (!(lane & 1) && node < N) {
                    const unsigned p = pack_bf2(v, o);
                    const long nb = node_off + node;
                    if (c < 128)      kv_u32[nb * 128 + c] = p;             // k-pair at even dword c
                    else if (c < 256) q_u32[nb * 64 + ((c - 128) >> 1)] = p;
                    else              kv_u32[nb * 128 + (c - 256) + 1] = p; // v-pair at odd dword
                }
            }
        }
    }
}

// ---------- K2: edge_feat MFMA: ef = [cos(rel_t*tw+tb) | msg | 0] @ W_edge + b_edge ----------
#define EFM 64
__global__ __launch_bounds__(256) void edgefeat_mfma_kernel(
    const float* __restrict__ last_update, const int* __restrict__ ei,
    const float* __restrict__ tvec, const float* __restrict__ msg,
    const float* __restrict__ time_w, const float* __restrict__ time_b,
    const unsigned short* __restrict__ Wt, const float* __restrict__ b_edge,
    unsigned* __restrict__ ef_u32, long out_off)
{
    __shared__ unsigned feat[EFM][100];          // pair-packed bf16, K=192 in dwords 0..95
    __shared__ float rts[EFM];
    const int tid = threadIdx.x;
    const int lane = tid & 63;
    const int wv = tid >> 6;
    const long e0 = (long)blockIdx.x * EFM;      // EE % 64 == 0

    if (tid < EFM) rts[tid] = last_update[ei[e0 + tid]] - tvec[e0 + tid];
    __syncthreads();
    for (int idx = tid; idx < EFM * 50; idx += 256) {       // time-enc -> dwords 0..49
        const int e = idx / 50, j = idx - e * 50;
        const float r = rts[e];
        const float c0 = __cosf(fmaf(r, time_w[2 * j], time_b[2 * j]));
        const float c1 = __cosf(fmaf(r, time_w[2 * j + 1], time_b[2 * j + 1]));
        feat[e][j] = pack_bf2(c0, c1);
    }
    for (int idx = tid; idx < EFM * 32; idx += 256) {       // msg -> dwords 50..81
        const int e = idx >> 5, j = idx & 31;
        const float2 mv = *reinterpret_cast<const float2*>(msg + (e0 + e) * 64 + 2 * j);
        feat[e][50 + j] = pack_bf2(mv.x, mv.y);
    }
    for (int idx = tid; idx < EFM * 18; idx += 256) {       // zero-pad -> dwords 82..99
        const int e = idx / 18, j = idx - e * 18;
        feat[e][82 + j] = 0u;
    }
    __syncthreads();

    const int m = lane & 15;
    const int kq = lane >> 4;
    f32x4 acc[4];
    #pragma unroll
    for (int nf = 0; nf < 4; ++nf) acc[nf] = (f32x4){0.f, 0.f, 0.f, 0.f};

    #pragma unroll
    for (int ks = 0; ks < 6; ++ks) {
        const bf16x8 a = *reinterpret_cast<const bf16x8*>(&feat[wv * 16 + m][ks * 16 + kq * 4]);
        #pragma unroll
        for (int nf = 0; nf < 4; ++nf) {
            const bf16x8 b = *reinterpret_cast<const bf16x8*>(Wt + (long)(nf * 16 + m) * 192 + ks * 32 + kq * 8);
            acc[nf] = __builtin_amdgcn_mfma_f32_16x16x32_bf16(a, b, acc[nf], 0, 0, 0);
        }
    }

    #pragma unroll
    for (int nf = 0; nf < 4; ++nf) {
        const int c = nf * 16 + m;
        const float bc = b_edge[c];
        #pragma unroll
        for (int reg = 0; reg < 4; ++reg) {
            const float v = acc[nf][reg] + bc;
            const float o = __shfl_xor(v, 1);
            if (!(lane & 1)) {
                const long ee = out_off + e0 + wv * 16 + kq * 4 + reg;
                ef_u32[ee * 32 + (c >> 1)] = pack_bf2(v, o);
            }
        }
    }
}

// ---------- CSR build ----------
__global__ __launch_bounds__(256) void count_kernel(
    const int* __restrict__ eiAB, const int* __restrict__ eiBA, int* __restrict__ cnt)
{
    const int ee = blockIdx.x * 256 + threadIdx.x;
    if (ee >= 2 * EE) return;
    const int dst = (ee < EE) ? (eiAB[EE + ee] + NA) : eiBA[EE + (ee - EE)];
    atomicAdd(&cnt[dst], 1);
}

__global__ __launch_bounds__(1024) void scan1_kernel(
    const int* __restrict__ cnt, int* __restrict__ offsets, int* __restrict__ bsum)
{
    __shared__ int tmp[1024];
    const int t = threadIdx.x;
    const int i = blockIdx.x * 1024 + t;
    const int v = (i < NTOT) ? cnt[i] : 0;
    tmp[t] = v;
    __syncthreads();
    for (int off = 1; off < 1024; off <<= 1) {
        const int u = (t >= off) ? tmp[t - off] : 0;
        __syncthreads();
        tmp[t] += u;
        __syncthreads();
    }
    offsets[i] = tmp[t] - v;
    if (t == 1023) bsum[blockIdx.x] = tmp[1023];
}

__global__ __launch_bounds__(256) void scan2_kernel(
    const int* __restrict__ bsum, int* __restrict__ bbase, int nblk)
{
    __shared__ int tmp[256];
    const int t = threadIdx.x;
    const int v = (t < nblk) ? bsum[t] : 0;
    tmp[t] = v;
    __syncthreads();
    for (int off = 1; off < 256; off <<= 1) {
        const int u = (t >= off) ? tmp[t - off] : 0;
        __syncthreads();
        tmp[t] += u;
        __syncthreads();
    }
    bbase[t] = tmp[t] - v;
}

__global__ __launch_bounds__(1024) void scan3_kernel(
    int* __restrict__ offsets, const int* __restrict__ bbase, int* __restrict__ cnt)
{
    const int t = threadIdx.x;
    const int i = blockIdx.x * 1024 + t;
    const int o = offsets[i] + bbase[blockIdx.x];
    offsets[i] = o;
    if (i < NTOT) cnt[i] = o;
    if (blockIdx.x == 0 && t == 0) offsets[NTOT] = 2 * EE;
}

__global__ __launch_bounds__(256) void fill_kernel(
    const int* __restrict__ eiAB, const int* __restrict__ eiBA,
    int* __restrict__ cursor, int* __restrict__ csr_src, int* __restrict__ csr_ee)
{
    const int ee = blockIdx.x * 256 + threadIdx.x;
    if (ee >= 2 * EE) return;
    int src, dst;
    if (ee < EE) { src = eiAB[ee];               dst = eiAB[EE + ee] + NA; }
    else { const int e = ee - EE; src = eiBA[e] + NA; dst = eiBA[EE + e]; }
    const int pos = atomicAdd(&cursor[dst], 1);
    csr_src[pos] = src;
    csr_ee[pos] = ee;
}

// ---------- K3: fused flash-softmax gather + gelu, writes g (bf16) into d_out ----------
__global__ __launch_bounds__(256) void gather_kernel(
    const unsigned* __restrict__ qb, const uint2* __restrict__ kv,
    const unsigned short* __restrict__ ef,
    const int* __restrict__ offsets, const int* __restrict__ csr_src, const int* __restrict__ csr_ee,
    const float* __restrict__ p_rel_AB, const float* __restrict__ p_rel_BA,
    unsigned short* __restrict__ g)
{
    const int lane = threadIdx.x & 63;
    const int wv = threadIdx.x >> 6;
    const int d0 = blockIdx.x * 16 + wv * 4;     // 12500 blocks, exact
    const int h = lane >> 5;
    const float sAB = p_rel_AB[h] * 0.125f;
    const float sBA = p_rel_BA[h] * 0.125f;

    for (int r = 0; r < 4; ++r) {
        const int d = d0 + r;
        const unsigned q2 = qb[(long)d * 64 + lane];
        const float ql = bf_lo(q2), qh = bf_hi(q2);
        float accv0 = 0.f, accv1 = 0.f, acce0 = 0.f, acce1 = 0.f, den = 0.f;
        const int beg = offsets[d], end = offsets[d + 1];
        for (int p = beg; p < end; ++p) {
            const int src = csr_src[p];
            const int ee = csr_ee[p];
            const uint2 kvd = kv[(long)src * 64 + lane];
            float partial = fmaf(ql, bf_lo(kvd.x), qh * bf_hi(kvd.x));
            #pragma unroll
            for (int m = 1; m <= 16; m <<= 1) partial += __shfl_xor(partial, m);
            const float s = (ee < EE) ? sAB : sBA;
            const float e = expf(partial * s);
            const float efv = __uint_as_float((unsigned)ef[(long)ee * 64 + lane] << 16);
            const float e_oth = __shfl_xor(e, 32);
            const float eh0 = (lane < 32) ? e : e_oth;
            const float eh1 = (lane < 32) ? e_oth : e;
            accv0 = fmaf(e, bf_lo(kvd.y), accv0);
            accv1 = fmaf(e, bf_hi(kvd.y), accv1);
            acce0 = fmaf(eh0, efv, acce0);
            acce1 = fmaf(eh1, efv, acce1);
            den += e;
        }
        const float inv = 1.f / (den + 1e-16f);
        const float inv_oth = __shfl_xor(inv, 32);
        const float inv0 = (lane < 32) ? inv : inv_oth;
        const float inv1 = (lane < 32) ? inv_oth : inv;
        const float gv0 = gelu_exact(accv0 * inv);
        const float gv1 = gelu_exact(accv1 * inv);
        const float ge0 = gelu_exact(acce0 * inv0);
        const float ge1 = gelu_exact(acce1 * inv1);
        unsigned short* gp = g + (long)d * 256;
        *reinterpret_cast<unsigned*>(gp + 2 * lane + ((lane < 32) ? 0 : 64)) = pack_bf2(gv0, gv1);
        gp[64 + lane] = (unsigned short)bf16rne(ge0);
        gp[192 + lane] = (unsigned short)bf16rne(ge1);
    }
}

// ---------- K4: MFMA out-projection: out = skip-gate( g @ W_out + b ), in-place over g ----------
__global__ __launch_bounds__(256) void proj_mfma_kernel(
    const short* __restrict__ g,
    const float* __restrict__ W_out, const float* __restrict__ b_out,
    const float* __restrict__ x, const float* __restrict__ skip,
    float* __restrict__ out, int roff, int N)
{
    __shared__ unsigned short Wt[128 * 264];
    const int tid = threadIdx.x;
    const int lane = tid & 63;
    const int wv = tid >> 6;

    for (int idx = tid; idx < 256 * 128; idx += 256) {
        const int k = idx >> 7, n = idx & 127;
        Wt[n * 264 + k] = (unsigned short)bf16rne(W_out[idx]);
    }
    __syncthreads();

    const int m0 = roff + blockIdx.x * 64 + wv * 16;
    const int rmax = roff + N - 1;
    const float ag = 1.f / (1.f + expf(-skip[0]));

    f32x4 acc[8];
    #pragma unroll
    for (int nf = 0; nf < 8; ++nf) acc[nf] = (f32x4){0.f, 0.f, 0.f, 0.f};

    const int arow = min(m0 + (lane & 15), rmax);
    const int kgrp = (lane >> 4) * 8;

    #pragma unroll
    for (int ks = 0; ks < 8; ++ks) {
        const bf16x8 a = *reinterpret_cast<const bf16x8*>(g + (long)arow * 256 + ks * 32 + kgrp);
        #pragma unroll
        for (int nf = 0; nf < 8; ++nf) {
            const bf16x8 b = *reinterpret_cast<const bf16x8*>(&Wt[(nf * 16 + (lane & 15)) * 264 + ks * 32 + kgrp]);
            acc[nf] = __builtin_amdgcn_mfma_f32_16x16x32_bf16(a, b, acc[nf], 0, 0, 0);
        }
    }

    #pragma unroll
    for (int nf = 0; nf < 8; ++nf) {
        const int col = nf * 16 + (lane & 15);
        const float bc = b_out[col];
        #pragma unroll
        for (int reg = 0; reg < 4; ++reg) {
            const int d = m0 + (lane >> 4) * 4 + reg;
            if (d <= rmax) {
                const float xv = x[(long)(d - roff) * 128 + col];
                out[(long)d * 128 + col] = fmaf(ag, acc[nf][reg] + bc, (1.f - ag) * xv);
            }
        }
    }
}

// ---------- launcher ----------
extern "C" void kernel_launch(void* const* d_in, const int* in_sizes, int n_in,
                              void* d_out, int out_size, void* d_ws, size_t ws_size,
                              hipStream_t stream) {
    const float* x_A     = (const float*)d_in[0];
    const float* x_B     = (const float*)d_in[1];
    const float* lu_A    = (const float*)d_in[2];
    const float* lu_B    = (const float*)d_in[3];
    const float* t_AB    = (const float*)d_in[4];
    const float* t_BA    = (const float*)d_in[5];
    const float* msg_AB  = (const float*)d_in[6];
    const float* msg_BA  = (const float*)d_in[7];
    const float* W_kqv_A = (const float*)d_in[8];
    const float* b_kqv_A = (const float*)d_in[9];
    const float* W_kqv_B = (const float*)d_in[10];
    const float* b_kqv_B = (const float*)d_in[11];
    const float* Wk_rel  = (const float*)d_in[12];
    const float* Wv_rel  = (const float*)d_in[13];
    const float* W_edge  = (const float*)d_in[14];
    const float* b_edge  = (const float*)d_in[15];
    const float* W_out_A = (const float*)d_in[16];
    const float* b_out_A = (const float*)d_in[17];
    const float* W_out_B = (const float*)d_in[18];
    const float* b_out_B = (const float*)d_in[19];
    const float* skip_A  = (const float*)d_in[20];
    const float* skip_B  = (const float*)d_in[21];
    const float* p_rel_AB= (const float*)d_in[22];
    const float* p_rel_BA= (const float*)d_in[23];
    const float* time_w  = (const float*)d_in[24];
    const float* time_b  = (const float*)d_in[25];
    const int*   eiAB    = (const int*)d_in[26];
    const int*   eiBA    = (const int*)d_in[27];
    float* out = (float*)d_out;

    // workspace layout (~264 MB)
    unsigned* q_bf  = (unsigned*)d_ws;                  // 12.8M u32
    unsigned* kvbuf = q_bf + 12800000;                  // 25.6M u32
    unsigned* efbuf = kvbuf + 25600000;                 // 25.6M u32
    int* cnt      = (int*)(efbuf + 25600000);           // 200000
    int* offsets  = cnt + 200000;                       // 210000
    int* csr_src  = offsets + 210000;                   // 800000
    int* csr_ee   = csr_src + 800000;                   // 800000
    unsigned short* WfA = (unsigned short*)(csr_ee + 800000);  // 49152 bf16
    unsigned short* WfB = WfA + 49152;                  // 49152 bf16
    float* bfA    = (float*)(WfB + 49152);              // 384
    float* bfB    = bfA + 384;                          // 384
    int* bsum     = (int*)(bfB + 384);                  // 256
    int* bbase    = bsum + 256;                         // 256
    unsigned short* Wet = (unsigned short*)(bbase + 256); // 12288 bf16

    (void)hipMemsetAsync(cnt, 0, (size_t)200000 * 4, stream);

    // CSR build
    count_kernel<<<(2 * EE + 255) / 256, 256, 0, stream>>>(eiAB, eiBA, cnt);
    scan1_kernel<<<196, 1024, 0, stream>>>(cnt, offsets, bsum);
    scan2_kernel<<<1, 256, 0, stream>>>(bsum, bbase, 196);
    scan3_kernel<<<196, 1024, 0, stream>>>(offsets, bbase, cnt);
    fill_kernel<<<(2 * EE + 255) / 256, 256, 0, stream>>>(eiAB, eiBA, cnt, csr_src, csr_ee);

    // weight prep
    fusew_kernel<<<384, 128, 0, stream>>>(W_kqv_A, b_kqv_A, Wk_rel, Wv_rel, 0, WfA, bfA);
    fusew_kernel<<<384, 128, 0, stream>>>(W_kqv_B, b_kqv_B, Wk_rel, Wv_rel, 1, WfB, bfB);
    wedget_kernel<<<64, 192, 0, stream>>>(W_edge, Wet);

    // MFMA kqv
    kqv_mfma_kernel<<<(NA + BM - 1) / BM, 256, 0, stream>>>(x_A, WfA, bfA, q_bf, kvbuf, NA, 0);
    kqv_mfma_kernel<<<(NB + BM - 1) / BM, 256, 0, stream>>>(x_B, WfB, bfB, q_bf, kvbuf, NB, NA);

    // MFMA edge features
    edgefeat_mfma_kernel<<<EE / EFM, 256, 0, stream>>>(lu_A, eiAB, t_AB, msg_AB, time_w, time_b,
                                                       Wet, b_edge, efbuf, 0L);
    edgefeat_mfma_kernel<<<EE / EFM, 256, 0, stream>>>(lu_B, eiBA, t_BA, msg_BA, time_w, time_b,
                                                       Wet, b_edge, efbuf, (long)EE);

    gather_kernel<<<NTOT / 16, 256, 0, stream>>>(q_bf, (const uint2*)kvbuf,
                                                 (const unsigned short*)efbuf,
                                                 offsets, csr_src, csr_ee,
                                                 p_rel_AB, p_rel_BA, (unsigned short*)out);

    proj_mfma_kernel<<<(NA + 63) / 64, 256, 0, stream>>>((const short*)out, W_out_A, b_out_A,
                                                         x_A, skip_A, out, 0, NA);
    proj_mfma_kernel<<<(NB + 63) / 64, 256, 0, stream>>>((const short*)out, W_out_B, b_out_B,
                                                         x_B, skip_B, out, NA, NB);
}

// Round 8
// 843.137 us; speedup vs baseline: 2.8324x; 1.1029x over previous
//
#include <hip/hip_runtime.h>
#include <math.h>

#define NA 100000
#define NB 100000
#define NTOT 200000
#define EE 400000      // edges per type
#define TDIM 100       // time encoder dim

typedef short bf16x8 __attribute__((ext_vector_type(8)));
typedef float f32x4 __attribute__((ext_vector_type(4)));

// ---------- helpers ----------
__device__ __forceinline__ float gelu_exact(float x) {
    return 0.5f * x * (1.0f + erff(x * 0.70710678118654752f));
}
__device__ __forceinline__ unsigned bf16rne(float f) {
    unsigned u = __float_as_uint(f);
    return (u + 0x7fffu + ((u >> 16) & 1u)) >> 16;
}
__device__ __forceinline__ unsigned pack_bf2(float lo, float hi) {
    return bf16rne(lo) | (bf16rne(hi) << 16);
}
__device__ __forceinline__ float bf_lo(unsigned u) { return __uint_as_float(u << 16); }
__device__ __forceinline__ float bf_hi(unsigned u) { return __uint_as_float(u & 0xffff0000u); }

// ---------- K0: fuse rel-transform into kqv weights (A and B in one grid) ----------
__global__ __launch_bounds__(128) void fusew_kernel(
    const float* __restrict__ W_A, const float* __restrict__ b_A,
    const float* __restrict__ W_B, const float* __restrict__ b_B,
    const float* __restrict__ Wk_rel, const float* __restrict__ Wv_rel,
    unsigned short* __restrict__ WfA, float* __restrict__ bfA,
    unsigned short* __restrict__ WfB, float* __restrict__ bfB)
{
    const int et = (blockIdx.x >= 384) ? 1 : 0;
    const int c = blockIdx.x - et * 384;       // 0..383
    const int i = threadIdx.x;                 // 0..127
    const float* __restrict__ W = et ? W_B : W_A;
    const float* __restrict__ b = et ? b_B : b_A;
    unsigned short* __restrict__ Wf_t = et ? WfB : WfA;
    float* __restrict__ bf = et ? bfB : bfA;

    float acc = 0.f;
    if (c < 128) {
        const int h = c >> 6, e = c & 63;
        const float* __restrict__ Wr = Wk_rel + (long)(h * 2 + et) * 4096;
        for (int d = 0; d < 64; ++d) acc += W[i * 384 + h * 64 + d] * Wr[d * 64 + e];
    } else if (c < 256) {
        acc = W[i * 384 + c];
    } else {
        const int h = (c - 256) >> 6, e = (c - 256) & 63;
        const float* __restrict__ Wr = Wv_rel + (long)(h * 2 + et) * 4096;
        for (int d = 0; d < 64; ++d) acc += W[i * 384 + 256 + h * 64 + d] * Wr[d * 64 + e];
    }
    Wf_t[c * 128 + i] = (unsigned short)bf16rne(acc);
    if (i == 0) {
        float bacc = 0.f;
        if (c < 128) {
            const int h = c >> 6, e = c & 63;
            const float* __restrict__ Wr = Wk_rel + (long)(h * 2 + et) * 4096;
            for (int d = 0; d < 64; ++d) bacc += b[h * 64 + d] * Wr[d * 64 + e];
        } else if (c < 256) {
            bacc = b[c];
        } else {
            const int h = (c - 256) >> 6, e = (c - 256) & 63;
            const float* __restrict__ Wr = Wv_rel + (long)(h * 2 + et) * 4096;
            for (int d = 0; d < 64; ++d) bacc += b[256 + h * 64 + d] * Wr[d * 64 + e];
        }
        bf[c] = bacc;
    }
}

// ---------- K0b: W_edge^T -> bf16 [64][192] (k padded 164->192) ----------
__global__ __launch_bounds__(192) void wedget_kernel(
    const float* __restrict__ W_edge, unsigned short* __restrict__ Wt)
{
    const int col = blockIdx.x;      // 0..63
    const int k = threadIdx.x;       // 0..191
    const float v = (k < 164) ? W_edge[k * 64 + col] : 0.f;
    Wt[col * 192 + k] = (unsigned short)bf16rne(v);
}

// ---------- K1: kqv MFMA GEMM (A and B in one grid) ----------
#define BM 64
__global__ __launch_bounds__(256) void kqv_mfma_kernel(
    const float* __restrict__ x_A, const float* __restrict__ x_B,
    const unsigned short* __restrict__ WfA, const unsigned short* __restrict__ WfB,
    const float* __restrict__ bfA, const float* __restrict__ bfB,
    unsigned* __restrict__ q_u32, unsigned* __restrict__ kv_u32, int nblkA)
{
    const bool isA = ((int)blockIdx.x < nblkA);
    const int blk = isA ? blockIdx.x : (blockIdx.x - nblkA);
    const float* __restrict__ x = isA ? x_A : x_B;
    const unsigned short* __restrict__ Wf_t = isA ? WfA : WfB;
    const float* __restrict__ bf = isA ? bfA : bfB;
    const int N = isA ? NA : NB;
    const int node_off = isA ? 0 : NA;

    __shared__ unsigned xs[BM][68];              // pair-packed bf16, +4 dword pad
    const int tid = threadIdx.x;
    const int lane = tid & 63;
    const int wv = tid >> 6;
    const int kq = lane >> 4;                    // k-group 0..3
    const int n0 = blk * BM;

    for (int idx = tid; idx < BM * 64; idx += 256) {
        const int n = idx >> 6, j = idx & 63;
        unsigned p = 0;
        const int node = n0 + n;
        if (node < N) {
            const float2 xv = *reinterpret_cast<const float2*>(x + (long)node * 128 + 2 * j);
            p = pack_bf2(xv.x, xv.y);
        }
        xs[n][j] = p;
    }
    __syncthreads();

    const int wq = wv * 96;                      // this wave's col base
    f32x4 acc[4][6];
    #pragma unroll
    for (int mt = 0; mt < 4; ++mt)
        #pragma unroll
        for (int nt = 0; nt < 6; ++nt) acc[mt][nt] = (f32x4){0.f, 0.f, 0.f, 0.f};

    #pragma unroll
    for (int ks = 0; ks < 4; ++ks) {
        bf16x8 a[4], bfr[6];
        #pragma unroll
        for (int mt = 0; mt < 4; ++mt)
            a[mt] = *reinterpret_cast<const bf16x8*>(&xs[mt * 16 + (lane & 15)][ks * 16 + kq * 4]);
        #pragma unroll
        for (int nt = 0; nt < 6; ++nt) {
            const int col = wq + nt * 16 + (lane & 15);
            bfr[nt] = *reinterpret_cast<const bf16x8*>(Wf_t + (long)col * 128 + ks * 32 + kq * 8);
        }
        #pragma unroll
        for (int mt = 0; mt < 4; ++mt)
            #pragma unroll
            for (int nt = 0; nt < 6; ++nt)
                acc[mt][nt] = __builtin_amdgcn_mfma_f32_16x16x32_bf16(a[mt], bfr[nt], acc[mt][nt], 0, 0, 0);
    }

    #pragma unroll
    for (int nt = 0; nt < 6; ++nt) {
        const int c = wq + nt * 16 + (lane & 15);
        const float bias_c = bf[c];
        #pragma unroll
        for (int mt = 0; mt < 4; ++mt) {
            #pragma unroll
            for (int reg = 0; reg < 4; ++reg) {
                const int node = n0 + mt * 16 + kq * 4 + reg;
                const float v = acc[mt][nt][reg] + bias_c;
                const float o = __shfl_xor(v, 1);
                if (!(lane & 1) && node < N) {
                    const unsigned p = pack_bf2(v, o);
                    const long nb = node_off + node;
                    if (c < 128)      kv_u32[nb * 128 + c] = p;             // k-pair at even dword c
                    else if (c < 256) q_u32[nb * 64 + ((c - 128) >> 1)] = p;
                    else              kv_u32[nb * 128 + (c - 256) + 1] = p; // v-pair at odd dword
                }
            }
        }
    }
}

// ---------- K2: edge_feat MFMA (both edge types in one grid) ----------
#define EFM 64
__global__ __launch_bounds__(256) void edgefeat_mfma_kernel(
    const float* __restrict__ lu_A, const float* __restrict__ lu_B,
    const int* __restrict__ eiAB, const int* __restrict__ eiBA,
    const float* __restrict__ t_AB, const float* __restrict__ t_BA,
    const float* __restrict__ msg_AB, const float* __restrict__ msg_BA,
    const float* __restrict__ time_w, const float* __restrict__ time_b,
    const unsigned short* __restrict__ Wt, const float* __restrict__ b_edge,
    unsigned* __restrict__ ef_u32, int nblkAB)
{
    const bool isAB = ((int)blockIdx.x < nblkAB);
    const int blk = isAB ? blockIdx.x : (blockIdx.x - nblkAB);
    const float* __restrict__ last_update = isAB ? lu_A : lu_B;
    const int* __restrict__ ei = isAB ? eiAB : eiBA;
    const float* __restrict__ tvec = isAB ? t_AB : t_BA;
    const float* __restrict__ msg = isAB ? msg_AB : msg_BA;
    const long out_off = isAB ? 0L : (long)EE;

    __shared__ unsigned feat[EFM][100];          // pair-packed bf16, K=192 in dwords 0..95
    __shared__ float rts[EFM];
    const int tid = threadIdx.x;
    const int lane = tid & 63;
    const int wv = tid >> 6;
    const long e0 = (long)blk * EFM;             // EE % 64 == 0

    if (tid < EFM) rts[tid] = last_update[ei[e0 + tid]] - tvec[e0 + tid];
    __syncthreads();
    for (int idx = tid; idx < EFM * 50; idx += 256) {       // time-enc -> dwords 0..49
        const int e = idx / 50, j = idx - e * 50;
        const float r = rts[e];
        const float c0 = __cosf(fmaf(r, time_w[2 * j], time_b[2 * j]));
        const float c1 = __cosf(fmaf(r, time_w[2 * j + 1], time_b[2 * j + 1]));
        feat[e][j] = pack_bf2(c0, c1);
    }
    for (int idx = tid; idx < EFM * 32; idx += 256) {       // msg -> dwords 50..81
        const int e = idx >> 5, j = idx & 31;
        const float2 mv = *reinterpret_cast<const float2*>(msg + (e0 + e) * 64 + 2 * j);
        feat[e][50 + j] = pack_bf2(mv.x, mv.y);
    }
    for (int idx = tid; idx < EFM * 18; idx += 256) {       // zero-pad -> dwords 82..99
        const int e = idx / 18, j = idx - e * 18;
        feat[e][82 + j] = 0u;
    }
    __syncthreads();

    const int m = lane & 15;
    const int kq = lane >> 4;
    f32x4 acc[4];
    #pragma unroll
    for (int nf = 0; nf < 4; ++nf) acc[nf] = (f32x4){0.f, 0.f, 0.f, 0.f};

    #pragma unroll
    for (int ks = 0; ks < 6; ++ks) {
        const bf16x8 a = *reinterpret_cast<const bf16x8*>(&feat[wv * 16 + m][ks * 16 + kq * 4]);
        #pragma unroll
        for (int nf = 0; nf < 4; ++nf) {
            const bf16x8 b = *reinterpret_cast<const bf16x8*>(Wt + (long)(nf * 16 + m) * 192 + ks * 32 + kq * 8);
            acc[nf] = __builtin_amdgcn_mfma_f32_16x16x32_bf16(a, b, acc[nf], 0, 0, 0);
        }
    }

    #pragma unroll
    for (int nf = 0; nf < 4; ++nf) {
        const int c = nf * 16 + m;
        const float bc = b_edge[c];
        #pragma unroll
        for (int reg = 0; reg < 4; ++reg) {
            const float v = acc[nf][reg] + bc;
            const float o = __shfl_xor(v, 1);
            if (!(lane & 1)) {
                const long ee = out_off + e0 + wv * 16 + kq * 4 + reg;
                ef_u32[ee * 32 + (c >> 1)] = pack_bf2(v, o);
            }
        }
    }
}

// ---------- CSR build ----------
__global__ __launch_bounds__(256) void count_kernel(
    const int* __restrict__ eiAB, const int* __restrict__ eiBA, int* __restrict__ cnt)
{
    const int ee = blockIdx.x * 256 + threadIdx.x;
    if (ee >= 2 * EE) return;
    const int dst = (ee < EE) ? (eiAB[EE + ee] + NA) : eiBA[EE + (ee - EE)];
    atomicAdd(&cnt[dst], 1);
}

__global__ __launch_bounds__(1024) void scan1_kernel(
    const int* __restrict__ cnt, int* __restrict__ offsets, int* __restrict__ bsum)
{
    __shared__ int tmp[1024];
    const int t = threadIdx.x;
    const int i = blockIdx.x * 1024 + t;
    const int v = (i < NTOT) ? cnt[i] : 0;
    tmp[t] = v;
    __syncthreads();
    for (int off = 1; off < 1024; off <<= 1) {
        const int u = (t >= off) ? tmp[t - off] : 0;
        __syncthreads();
        tmp[t] += u;
        __syncthreads();
    }
    offsets[i] = tmp[t] - v;
    if (t == 1023) bsum[blockIdx.x] = tmp[1023];
}

__global__ __launch_bounds__(256) void scan2_kernel(
    const int* __restrict__ bsum, int* __restrict__ bbase, int nblk)
{
    __shared__ int tmp[256];
    const int t = threadIdx.x;
    const int v = (t < nblk) ? bsum[t] : 0;
    tmp[t] = v;
    __syncthreads();
    for (int off = 1; off < 256; off <<= 1) {
        const int u = (t >= off) ? tmp[t - off] : 0;
        __syncthreads();
        tmp[t] += u;
        __syncthreads();
    }
    bbase[t] = tmp[t] - v;
}

__global__ __launch_bounds__(1024) void scan3_kernel(
    int* __restrict__ offsets, const int* __restrict__ bbase, int* __restrict__ cnt)
{
    const int t = threadIdx.x;
    const int i = blockIdx.x * 1024 + t;
    const int o = offsets[i] + bbase[blockIdx.x];
    offsets[i] = o;
    if (i < NTOT) cnt[i] = o;
    if (blockIdx.x == 0 && t == 0) offsets[NTOT] = 2 * EE;
}

__global__ __launch_bounds__(256) void fill_kernel(
    const int* __restrict__ eiAB, const int* __restrict__ eiBA,
    int* __restrict__ cursor, int* __restrict__ csr_src, int* __restrict__ csr_ee)
{
    const int ee = blockIdx.x * 256 + threadIdx.x;
    if (ee >= 2 * EE) return;
    int src, dst;
    if (ee < EE) { src = eiAB[ee];               dst = eiAB[EE + ee] + NA; }
    else { const int e = ee - EE; src = eiBA[e] + NA; dst = eiBA[EE + e]; }
    const int pos = atomicAdd(&cursor[dst], 1);
    csr_src[pos] = src;
    csr_ee[pos] = ee;
}

// ---------- K3: fused flash-softmax gather + gelu, 2 edges per wave ----------
// lane = 32*eh + 16*h + j : eh = edge slot, h = head, j = comp group (4 comps)
__global__ __launch_bounds__(256) void gather_kernel(
    const unsigned* __restrict__ qb, const uint4* __restrict__ kv,
    const unsigned* __restrict__ ef,
    const int* __restrict__ offsets, const int* __restrict__ csr_src, const int* __restrict__ csr_ee,
    const float* __restrict__ p_rel_AB, const float* __restrict__ p_rel_BA,
    unsigned* __restrict__ g)
{
    const int lane = threadIdx.x & 63;
    const int wv = threadIdx.x >> 6;
    const int eh = lane >> 5;
    const int h = (lane >> 4) & 1;
    const int j = lane & 15;
    const int c = 16 * h + j;                    // dword-pair index 0..31
    const int d0 = blockIdx.x * 16 + wv * 4;     // 12500 blocks, exact
    const float sAB = p_rel_AB[h] * 0.125f;
    const float sBA = p_rel_BA[h] * 0.125f;

    for (int r = 0; r < 4; ++r) {
        const int d = d0 + r;
        const uint2 q2 = *reinterpret_cast<const uint2*>(qb + (long)d * 64 + 2 * c);
        float av0 = 0.f, av1 = 0.f, av2 = 0.f, av3 = 0.f;
        float ae00 = 0.f, ae01 = 0.f, ae10 = 0.f, ae11 = 0.f;
        float den = 0.f;
        const int beg = offsets[d], end = offsets[d + 1];
        for (int p0 = beg; p0 < end; p0 += 2) {
            const int p = p0 + eh;
            const bool valid = (p < end);
            const int pc = valid ? p : p0;
            const int src = csr_src[pc];
            const int ee = csr_ee[pc];
            const uint4 kvd = kv[(long)src * 32 + c];
            float partial = fmaf(bf_lo(q2.x), bf_lo(kvd.x),
                            fmaf(bf_hi(q2.x), bf_hi(kvd.x),
                            fmaf(bf_lo(q2.y), bf_lo(kvd.z),
                                 bf_hi(q2.y) * bf_hi(kvd.z))));
            partial += __shfl_xor(partial, 1);
            partial += __shfl_xor(partial, 2);
            partial += __shfl_xor(partial, 4);
            partial += __shfl_xor(partial, 8);
            const float s = (ee < EE) ? sAB : sBA;
            float e = valid ? expf(partial * s) : 0.f;
            const unsigned efd = ef[(long)ee * 32 + c];
            const float ef0 = bf_lo(efd), ef1 = bf_hi(efd);
            const float e_oth = __shfl_xor(e, 16);
            const float w0 = h ? e_oth : e;      // head-0 softmax weight
            const float w1 = h ? e : e_oth;      // head-1 softmax weight
            av0 = fmaf(e, bf_lo(kvd.y), av0);
            av1 = fmaf(e, bf_hi(kvd.y), av1);
            av2 = fmaf(e, bf_lo(kvd.w), av2);
            av3 = fmaf(e, bf_hi(kvd.w), av3);
            ae00 = fmaf(w0, ef0, ae00);
            ae01 = fmaf(w0, ef1, ae01);
            ae10 = fmaf(w1, ef0, ae10);
            ae11 = fmaf(w1, ef1, ae11);
            den += e;
        }
        // merge the two edge-slot halves
        av0 += __shfl_xor(av0, 32);
        av1 += __shfl_xor(av1, 32);
        av2 += __shfl_xor(av2, 32);
        av3 += __shfl_xor(av3, 32);
        ae00 += __shfl_xor(ae00, 32);
        ae01 += __shfl_xor(ae01, 32);
        ae10 += __shfl_xor(ae10, 32);
        ae11 += __shfl_xor(ae11, 32);
        den += __shfl_xor(den, 32);

        const float inv = 1.f / (den + 1e-16f);          // own head's inverse denom
        const float inv_oth = __shfl_xor(inv, 16);
        const float inv0 = h ? inv_oth : inv;
        const float inv1 = h ? inv : inv_oth;

        if (eh == 0) {
            const float gv0 = gelu_exact(av0 * inv);
            const float gv1 = gelu_exact(av1 * inv);
            const float gv2 = gelu_exact(av2 * inv);
            const float gv3 = gelu_exact(av3 * inv);
            const float ge00 = gelu_exact(ae00 * inv0);
            const float ge01 = gelu_exact(ae01 * inv0);
            const float ge10 = gelu_exact(ae10 * inv1);
            const float ge11 = gelu_exact(ae11 * inv1);
            unsigned* gp = g + (long)d * 128;
            const int vb = h ? (64 + 2 * j) : (2 * j);   // v block dword base
            gp[vb]     = pack_bf2(gv0, gv1);
            gp[vb + 1] = pack_bf2(gv2, gv3);
            gp[32 + c] = pack_bf2(ge00, ge01);           // ef, head-0 block
            gp[96 + c] = pack_bf2(ge10, ge11);           // ef, head-1 block
        }
    }
}

// ---------- K4: MFMA out-projection (A and B in one grid), in-place over g ----------
__global__ __launch_bounds__(256) void proj_mfma_kernel(
    const short* __restrict__ g,
    const float* __restrict__ W_out_A, const float* __restrict__ b_out_A,
    const float* __restrict__ W_out_B, const float* __restrict__ b_out_B,
    const float* __restrict__ x_A, const float* __restrict__ x_B,
    const float* __restrict__ skip_A, const float* __restrict__ skip_B,
    float* __restrict__ out, int nblkA)
{
    const bool isA = ((int)blockIdx.x < nblkA);
    const int blk = isA ? blockIdx.x : (blockIdx.x - nblkA);
    const float* __restrict__ W_out = isA ? W_out_A : W_out_B;
    const float* __restrict__ b_out = isA ? b_out_A : b_out_B;
    const float* __restrict__ x = isA ? x_A : x_B;
    const float* __restrict__ skip = isA ? skip_A : skip_B;
    const int roff = isA ? 0 : NA;
    const int N = isA ? NA : NB;

    __shared__ unsigned short Wt[128 * 264];
    const int tid = threadIdx.x;
    const int lane = tid & 63;
    const int wv = tid >> 6;

    for (int idx = tid; idx < 256 * 128; idx += 256) {
        const int k = idx >> 7, n = idx & 127;
        Wt[n * 264 + k] = (unsigned short)bf16rne(W_out[idx]);
    }
    __syncthreads();

    const int m0 = roff + blk * 64 + wv * 16;
    const int rmax = roff + N - 1;
    const float ag = 1.f / (1.f + expf(-skip[0]));

    f32x4 acc[8];
    #pragma unroll
    for (int nf = 0; nf < 8; ++nf) acc[nf] = (f32x4){0.f, 0.f, 0.f, 0.f};

    const int arow = min(m0 + (lane & 15), rmax);
    const int kgrp = (lane >> 4) * 8;

    #pragma unroll
    for (int ks = 0; ks < 8; ++ks) {
        const bf16x8 a = *reinterpret_cast<const bf16x8*>(g + (long)arow * 256 + ks * 32 + kgrp);
        #pragma unroll
        for (int nf = 0; nf < 8; ++nf) {
            const bf16x8 b = *reinterpret_cast<const bf16x8*>(&Wt[(nf * 16 + (lane & 15)) * 264 + ks * 32 + kgrp]);
            acc[nf] = __builtin_amdgcn_mfma_f32_16x16x32_bf16(a, b, acc[nf], 0, 0, 0);
        }
    }

    #pragma unroll
    for (int nf = 0; nf < 8; ++nf) {
        const int col = nf * 16 + (lane & 15);
        const float bc = b_out[col];
        #pragma unroll
        for (int reg = 0; reg < 4; ++reg) {
            const int d = m0 + (lane >> 4) * 4 + reg;
            if (d <= rmax) {
                const float xv = x[(long)(d - roff) * 128 + col];
                out[(long)d * 128 + col] = fmaf(ag, acc[nf][reg] + bc, (1.f - ag) * xv);
            }
        }
    }
}

// ---------- launcher ----------
extern "C" void kernel_launch(void* const* d_in, const int* in_sizes, int n_in,
                              void* d_out, int out_size, void* d_ws, size_t ws_size,
                              hipStream_t stream) {
    const float* x_A     = (const float*)d_in[0];
    const float* x_B     = (const float*)d_in[1];
    const float* lu_A    = (const float*)d_in[2];
    const float* lu_B    = (const float*)d_in[3];
    const float* t_AB    = (const float*)d_in[4];
    const float* t_BA    = (const float*)d_in[5];
    const float* msg_AB  = (const float*)d_in[6];
    const float* msg_BA  = (const float*)d_in[7];
    const float* W_kqv_A = (const float*)d_in[8];
    const float* b_kqv_A = (const float*)d_in[9];
    const float* W_kqv_B = (const float*)d_in[10];
    const float* b_kqv_B = (const float*)d_in[11];
    const float* Wk_rel  = (const float*)d_in[12];
    const float* Wv_rel  = (const float*)d_in[13];
    const float* W_edge  = (const float*)d_in[14];
    const float* b_edge  = (const float*)d_in[15];
    const float* W_out_A = (const float*)d_in[16];
    const float* b_out_A = (const float*)d_in[17];
    const float* W_out_B = (const float*)d_in[18];
    const float* b_out_B = (const float*)d_in[19];
    const float* skip_A  = (const float*)d_in[20];
    const float* skip_B  = (const float*)d_in[21];
    const float* p_rel_AB= (const float*)d_in[22];
    const float* p_rel_BA= (const float*)d_in[23];
    const float* time_w  = (const float*)d_in[24];
    const float* time_b  = (const float*)d_in[25];
    const int*   eiAB    = (const int*)d_in[26];
    const int*   eiBA    = (const int*)d_in[27];
    float* out = (float*)d_out;

    // workspace layout (~264 MB)
    unsigned* q_bf  = (unsigned*)d_ws;                  // 12.8M u32
    unsigned* kvbuf = q_bf + 12800000;                  // 25.6M u32
    unsigned* efbuf = kvbuf + 25600000;                 // 25.6M u32
    int* cnt      = (int*)(efbuf + 25600000);           // 200000
    int* offsets  = cnt + 200000;                       // 210000
    int* csr_src  = offsets + 210000;                   // 800000
    int* csr_ee   = csr_src + 800000;                   // 800000
    unsigned short* WfA = (unsigned short*)(csr_ee + 800000);  // 49152 bf16
    unsigned short* WfB = WfA + 49152;                  // 49152 bf16
    float* bfA    = (float*)(WfB + 49152);              // 384
    float* bfB    = bfA + 384;                          // 384
    int* bsum     = (int*)(bfB + 384);                  // 256
    int* bbase    = bsum + 256;                         // 256
    unsigned short* Wet = (unsigned short*)(bbase + 256); // 12288 bf16

    (void)hipMemsetAsync(cnt, 0, (size_t)200000 * 4, stream);

    // CSR build
    count_kernel<<<(2 * EE + 255) / 256, 256, 0, stream>>>(eiAB, eiBA, cnt);
    scan1_kernel<<<196, 1024, 0, stream>>>(cnt, offsets, bsum);
    scan2_kernel<<<1, 256, 0, stream>>>(bsum, bbase, 196);
    scan3_kernel<<<196, 1024, 0, stream>>>(offsets, bbase, cnt);
    fill_kernel<<<(2 * EE + 255) / 256, 256, 0, stream>>>(eiAB, eiBA, cnt, csr_src, csr_ee);

    // weight prep
    fusew_kernel<<<768, 128, 0, stream>>>(W_kqv_A, b_kqv_A, W_kqv_B, b_kqv_B,
                                          Wk_rel, Wv_rel, WfA, bfA, WfB, bfB);
    wedget_kernel<<<64, 192, 0, stream>>>(W_edge, Wet);

    // MFMA kqv (A+B)
    const int nblkA = (NA + BM - 1) / BM;
    const int nblkB = (NB + BM - 1) / BM;
    kqv_mfma_kernel<<<nblkA + nblkB, 256, 0, stream>>>(x_A, x_B, WfA, WfB, bfA, bfB,
                                                       q_bf, kvbuf, nblkA);

    // MFMA edge features (AB+BA)
    edgefeat_mfma_kernel<<<2 * (EE / EFM), 256, 0, stream>>>(lu_A, lu_B, eiAB, eiBA,
                                                             t_AB, t_BA, msg_AB, msg_BA,
                                                             time_w, time_b, Wet, b_edge,
                                                             efbuf, EE / EFM);

    gather_kernel<<<NTOT / 16, 256, 0, stream>>>(q_bf, (const uint4*)kvbuf, efbuf,
                                                 offsets, csr_src, csr_ee,
                                                 p_rel_AB, p_rel_BA, (unsigned*)out);

    // MFMA out-projection (A+B)
    proj_mfma_kernel<<<2 * 1563, 256, 0, stream>>>((const short*)out,
                                                   W_out_A, b_out_A, W_out_B, b_out_B,
                                                   x_A, x_B, skip_A, skip_B, out, 1563);
}

// Round 9
// 804.256 us; speedup vs baseline: 2.9693x; 1.0483x over previous
//
#include <hip/hip_runtime.h>
#include <math.h>

#define NA 100000
#define NB 100000
#define NTOT 200000
#define EE 400000      // edges per type
#define TDIM 100       // time encoder dim
#define NTILE (EE / 16)

typedef short bf16x8 __attribute__((ext_vector_type(8)));
typedef float f32x4 __attribute__((ext_vector_type(4)));

// ---------- helpers ----------
__device__ __forceinline__ float gelu_exact(float x) {
    return 0.5f * x * (1.0f + erff(x * 0.70710678118654752f));
}
__device__ __forceinline__ unsigned bf16rne(float f) {
    unsigned u = __float_as_uint(f);
    return (u + 0x7fffu + ((u >> 16) & 1u)) >> 16;
}
__device__ __forceinline__ unsigned pack_bf2(float lo, float hi) {
    return bf16rne(lo) | (bf16rne(hi) << 16);
}
__device__ __forceinline__ float bf_lo(unsigned u) { return __uint_as_float(u << 16); }
__device__ __forceinline__ float bf_hi(unsigned u) { return __uint_as_float(u & 0xffff0000u); }

// ---------- K0: fuse rel-transform into kqv weights (A and B in one grid) ----------
__global__ __launch_bounds__(128) void fusew_kernel(
    const float* __restrict__ W_A, const float* __restrict__ b_A,
    const float* __restrict__ W_B, const float* __restrict__ b_B,
    const float* __restrict__ Wk_rel, const float* __restrict__ Wv_rel,
    unsigned short* __restrict__ WfA, float* __restrict__ bfA,
    unsigned short* __restrict__ WfB, float* __restrict__ bfB)
{
    const int et = (blockIdx.x >= 384) ? 1 : 0;
    const int c = blockIdx.x - et * 384;       // 0..383
    const int i = threadIdx.x;                 // 0..127
    const float* __restrict__ W = et ? W_B : W_A;
    const float* __restrict__ b = et ? b_B : b_A;
    unsigned short* __restrict__ Wf_t = et ? WfB : WfA;
    float* __restrict__ bf = et ? bfB : bfA;

    float acc = 0.f;
    if (c < 128) {
        const int h = c >> 6, e = c & 63;
        const float* __restrict__ Wr = Wk_rel + (long)(h * 2 + et) * 4096;
        for (int d = 0; d < 64; ++d) acc += W[i * 384 + h * 64 + d] * Wr[d * 64 + e];
    } else if (c < 256) {
        acc = W[i * 384 + c];
    } else {
        const int h = (c - 256) >> 6, e = (c - 256) & 63;
        const float* __restrict__ Wr = Wv_rel + (long)(h * 2 + et) * 4096;
        for (int d = 0; d < 64; ++d) acc += W[i * 384 + 256 + h * 64 + d] * Wr[d * 64 + e];
    }
    Wf_t[c * 128 + i] = (unsigned short)bf16rne(acc);
    if (i == 0) {
        float bacc = 0.f;
        if (c < 128) {
            const int h = c >> 6, e = c & 63;
            const float* __restrict__ Wr = Wk_rel + (long)(h * 2 + et) * 4096;
            for (int d = 0; d < 64; ++d) bacc += b[h * 64 + d] * Wr[d * 64 + e];
        } else if (c < 256) {
            bacc = b[c];
        } else {
            const int h = (c - 256) >> 6, e = (c - 256) & 63;
            const float* __restrict__ Wr = Wv_rel + (long)(h * 2 + et) * 4096;
            for (int d = 0; d < 64; ++d) bacc += b[256 + h * 64 + d] * Wr[d * 64 + e];
        }
        bf[c] = bacc;
    }
}

// ---------- K0b: W_edge^T -> bf16 [64][192] (k padded 164->192) ----------
__global__ __launch_bounds__(192) void wedget_kernel(
    const float* __restrict__ W_edge, unsigned short* __restrict__ Wt)
{
    const int col = blockIdx.x;      // 0..63
    const int k = threadIdx.x;       // 0..191
    const float v = (k < 164) ? W_edge[k * 64 + col] : 0.f;
    Wt[col * 192 + k] = (unsigned short)bf16rne(v);
}

// ---------- K1: kqv MFMA GEMM (A and B in one grid) ----------
#define BM 64
__global__ __launch_bounds__(256) void kqv_mfma_kernel(
    const float* __restrict__ x_A, const float* __restrict__ x_B,
    const unsigned short* __restrict__ WfA, const unsigned short* __restrict__ WfB,
    const float* __restrict__ bfA, const float* __restrict__ bfB,
    unsigned* __restrict__ q_u32, unsigned* __restrict__ kv_u32, int nblkA)
{
    const bool isA = ((int)blockIdx.x < nblkA);
    const int blk = isA ? blockIdx.x : (blockIdx.x - nblkA);
    const float* __restrict__ x = isA ? x_A : x_B;
    const unsigned short* __restrict__ Wf_t = isA ? WfA : WfB;
    const float* __restrict__ bf = isA ? bfA : bfB;
    const int N = isA ? NA : NB;
    const int node_off = isA ? 0 : NA;

    __shared__ unsigned xs[BM][68];              // pair-packed bf16, +4 dword pad
    const int tid = threadIdx.x;
    const int lane = tid & 63;
    const int wv = tid >> 6;
    const int kq = lane >> 4;                    // k-group 0..3
    const int n0 = blk * BM;

    for (int idx = tid; idx < BM * 64; idx += 256) {
        const int n = idx >> 6, j = idx & 63;
        unsigned p = 0;
        const int node = n0 + n;
        if (node < N) {
            const float2 xv = *reinterpret_cast<const float2*>(x + (long)node * 128 + 2 * j);
            p = pack_bf2(xv.x, xv.y);
        }
        xs[n][j] = p;
    }
    __syncthreads();

    const int wq = wv * 96;                      // this wave's col base
    f32x4 acc[4][6];
    #pragma unroll
    for (int mt = 0; mt < 4; ++mt)
        #pragma unroll
        for (int nt = 0; nt < 6; ++nt) acc[mt][nt] = (f32x4){0.f, 0.f, 0.f, 0.f};

    #pragma unroll
    for (int ks = 0; ks < 4; ++ks) {
        bf16x8 a[4], bfr[6];
        #pragma unroll
        for (int mt = 0; mt < 4; ++mt)
            a[mt] = *reinterpret_cast<const bf16x8*>(&xs[mt * 16 + (lane & 15)][ks * 16 + kq * 4]);
        #pragma unroll
        for (int nt = 0; nt < 6; ++nt) {
            const int col = wq + nt * 16 + (lane & 15);
            bfr[nt] = *reinterpret_cast<const bf16x8*>(Wf_t + (long)col * 128 + ks * 32 + kq * 8);
        }
        #pragma unroll
        for (int mt = 0; mt < 4; ++mt)
            #pragma unroll
            for (int nt = 0; nt < 6; ++nt)
                acc[mt][nt] = __builtin_amdgcn_mfma_f32_16x16x32_bf16(a[mt], bfr[nt], acc[mt][nt], 0, 0, 0);
    }

    #pragma unroll
    for (int nt = 0; nt < 6; ++nt) {
        const int c = wq + nt * 16 + (lane & 15);
        const float bias_c = bf[c];
        #pragma unroll
        for (int mt = 0; mt < 4; ++mt) {
            #pragma unroll
            for (int reg = 0; reg < 4; ++reg) {
                const int node = n0 + mt * 16 + kq * 4 + reg;
                const float v = acc[mt][nt][reg] + bias_c;
                const float o = __shfl_xor(v, 1);
                if (!(lane & 1) && node < N) {
                    const unsigned p = pack_bf2(v, o);
                    const long nb = node_off + node;
                    if (c < 128)      kv_u32[nb * 128 + c] = p;             // k-pair at even dword c
                    else if (c < 256) q_u32[nb * 64 + ((c - 128) >> 1)] = p;
                    else              kv_u32[nb * 128 + (c - 256) + 1] = p; // v-pair at odd dword
                }
            }
        }
    }
}

// ---------- K2: edge_feat, wave-synchronous: one wave = 16 edges, no barriers ----------
__global__ __launch_bounds__(256) void edgefeat_wave_kernel(
    const float* __restrict__ lu_A, const float* __restrict__ lu_B,
    const int* __restrict__ eiAB, const int* __restrict__ eiBA,
    const float* __restrict__ t_AB, const float* __restrict__ t_BA,
    const float* __restrict__ msg_AB, const float* __restrict__ msg_BA,
    const float* __restrict__ time_w, const float* __restrict__ time_b,
    const unsigned short* __restrict__ Wt, const float* __restrict__ b_edge,
    unsigned* __restrict__ ef_u32)
{
    __shared__ unsigned feat[4][16][100];        // per-wave 6.4KB slab, K=192 bf16 in dwords 0..95
    const int tid = threadIdx.x;
    const int lane = tid & 63;
    const int wv = tid >> 6;
    const int gw = blockIdx.x * 4 + wv;          // 0..49999
    const bool isAB = gw < NTILE;
    const int tile = isAB ? gw : gw - NTILE;
    const float* __restrict__ lu   = isAB ? lu_A : lu_B;
    const int* __restrict__ ei     = isAB ? eiAB : eiBA;
    const float* __restrict__ tvec = isAB ? t_AB : t_BA;
    const float* __restrict__ msg  = isAB ? msg_AB : msg_BA;
    const long out_off = isAB ? 0L : (long)EE;
    const long e0 = (long)tile * 16;

    unsigned (* __restrict__ fw)[100] = feat[wv];

    // edge meta in lanes 0..15 (random lu gather issued first)
    float rts_l = 0.f;
    if (lane < 16) rts_l = lu[ei[e0 + lane]] - tvec[e0 + lane];

    // msg staging: lane -> edge e = lane>>2, quarter qt = lane&3 (16 floats -> 8 dwords)
    {
        const int e = lane >> 2, qt = lane & 3;
        const float* mp = msg + (e0 + e) * 64 + qt * 16;
        const float4 a0 = *reinterpret_cast<const float4*>(mp);
        const float4 a1 = *reinterpret_cast<const float4*>(mp + 4);
        const float4 a2 = *reinterpret_cast<const float4*>(mp + 8);
        const float4 a3 = *reinterpret_cast<const float4*>(mp + 12);
        uint2 w0, w1, w2, w3;
        w0.x = pack_bf2(a0.x, a0.y); w0.y = pack_bf2(a0.z, a0.w);
        w1.x = pack_bf2(a1.x, a1.y); w1.y = pack_bf2(a1.z, a1.w);
        w2.x = pack_bf2(a2.x, a2.y); w2.y = pack_bf2(a2.z, a2.w);
        w3.x = pack_bf2(a3.x, a3.y); w3.y = pack_bf2(a3.z, a3.w);
        *reinterpret_cast<uint2*>(&fw[e][50 + qt * 8])     = w0;
        *reinterpret_cast<uint2*>(&fw[e][50 + qt * 8 + 2]) = w1;
        *reinterpret_cast<uint2*>(&fw[e][50 + qt * 8 + 4]) = w2;
        *reinterpret_cast<uint2*>(&fw[e][50 + qt * 8 + 6]) = w3;
    }
    // time-encoding: 16 edges x 50 dwords = 800 dwords
    #pragma unroll
    for (int i = 0; i < 13; ++i) {
        const int idx = lane + (i << 6);
        if (idx < 800) {
            const int e = idx / 50, j = idx - e * 50;
            const float r = __shfl(rts_l, e);
            const float c0 = __cosf(fmaf(r, time_w[2 * j], time_b[2 * j]));
            const float c1 = __cosf(fmaf(r, time_w[2 * j + 1], time_b[2 * j + 1]));
            fw[e][j] = pack_bf2(c0, c1);
        }
    }
    // zero pad: dwords 82..99 per edge (K 164->192 bf16 + row tail)
    #pragma unroll
    for (int i = 0; i < 5; ++i) {
        const int idx = lane + (i << 6);
        if (idx < 288) {
            const int e = idx / 18, j = idx - e * 18;
            fw[e][82 + j] = 0u;
        }
    }
    // wave-local LDS write->read ordering (no __syncthreads needed)
    asm volatile("s_waitcnt lgkmcnt(0)" ::: "memory");

    const int m = lane & 15;
    const int kq = lane >> 4;
    f32x4 acc[4];
    #pragma unroll
    for (int nf = 0; nf < 4; ++nf) acc[nf] = (f32x4){0.f, 0.f, 0.f, 0.f};

    #pragma unroll
    for (int ks = 0; ks < 6; ++ks) {
        const bf16x8 a = *reinterpret_cast<const bf16x8*>(&fw[m][ks * 16 + kq * 4]);
        #pragma unroll
        for (int nf = 0; nf < 4; ++nf) {
            const bf16x8 b = *reinterpret_cast<const bf16x8*>(Wt + (long)(nf * 16 + m) * 192 + ks * 32 + kq * 8);
            acc[nf] = __builtin_amdgcn_mfma_f32_16x16x32_bf16(a, b, acc[nf], 0, 0, 0);
        }
    }

    #pragma unroll
    for (int nf = 0; nf < 4; ++nf) {
        const int c = nf * 16 + m;
        const float bc = b_edge[c];
        #pragma unroll
        for (int reg = 0; reg < 4; ++reg) {
            const float v = acc[nf][reg] + bc;
            const float o = __shfl_xor(v, 1);
            if (!(lane & 1)) {
                const long ee = out_off + e0 + kq * 4 + reg;
                ef_u32[ee * 32 + (c >> 1)] = pack_bf2(v, o);
            }
        }
    }
}

// ---------- CSR build ----------
__global__ __launch_bounds__(256) void count_kernel(
    const int* __restrict__ eiAB, const int* __restrict__ eiBA, int* __restrict__ cnt)
{
    const int ee = blockIdx.x * 256 + threadIdx.x;
    if (ee >= 2 * EE) return;
    const int dst = (ee < EE) ? (eiAB[EE + ee] + NA) : eiBA[EE + (ee - EE)];
    atomicAdd(&cnt[dst], 1);
}

__global__ __launch_bounds__(1024) void scan1_kernel(
    const int* __restrict__ cnt, int* __restrict__ offsets, int* __restrict__ bsum)
{
    __shared__ int tmp[1024];
    const int t = threadIdx.x;
    const int i = blockIdx.x * 1024 + t;
    const int v = (i < NTOT) ? cnt[i] : 0;
    tmp[t] = v;
    __syncthreads();
    for (int off = 1; off < 1024; off <<= 1) {
        const int u = (t >= off) ? tmp[t - off] : 0;
        __syncthreads();
        tmp[t] += u;
        __syncthreads();
    }
    offsets[i] = tmp[t] - v;
    if (t == 1023) bsum[blockIdx.x] = tmp[1023];
}

__global__ __launch_bounds__(256) void scan2_kernel(
    const int* __restrict__ bsum, int* __restrict__ bbase, int nblk)
{
    __shared__ int tmp[256];
    const int t = threadIdx.x;
    const int v = (t < nblk) ? bsum[t] : 0;
    tmp[t] = v;
    __syncthreads();
    for (int off = 1; off < 256; off <<= 1) {
        const int u = (t >= off) ? tmp[t - off] : 0;
        __syncthreads();
        tmp[t] += u;
        __syncthreads();
    }
    bbase[t] = tmp[t] - v;
}

__global__ __launch_bounds__(1024) void scan3_kernel(
    int* __restrict__ offsets, const int* __restrict__ bbase, int* __restrict__ cnt)
{
    const int t = threadIdx.x;
    const int i = blockIdx.x * 1024 + t;
    const int o = offsets[i] + bbase[blockIdx.x];
    offsets[i] = o;
    if (i < NTOT) cnt[i] = o;
    if (blockIdx.x == 0 && t == 0) offsets[NTOT] = 2 * EE;
}

__global__ __launch_bounds__(256) void fill_kernel(
    const int* __restrict__ eiAB, const int* __restrict__ eiBA,
    int* __restrict__ cursor, int* __restrict__ csr_src, int* __restrict__ csr_ee)
{
    const int ee = blockIdx.x * 256 + threadIdx.x;
    if (ee >= 2 * EE) return;
    int src, dst;
    if (ee < EE) { src = eiAB[ee];               dst = eiAB[EE + ee] + NA; }
    else { const int e = ee - EE; src = eiBA[e] + NA; dst = eiBA[EE + e]; }
    const int pos = atomicAdd(&cursor[dst], 1);
    csr_src[pos] = src;
    csr_ee[pos] = ee;
}

// ---------- K3: fused flash-softmax gather + gelu, 2 edges per wave ----------
// lane = 32*eh + 16*h + j : eh = edge slot, h = head, j = comp group (4 comps)
__global__ __launch_bounds__(256) void gather_kernel(
    const unsigned* __restrict__ qb, const uint4* __restrict__ kv,
    const unsigned* __restrict__ ef,
    const int* __restrict__ offsets, const int* __restrict__ csr_src, const int* __restrict__ csr_ee,
    const float* __restrict__ p_rel_AB, const float* __restrict__ p_rel_BA,
    unsigned* __restrict__ g)
{
    const int lane = threadIdx.x & 63;
    const int wv = threadIdx.x >> 6;
    const int eh = lane >> 5;
    const int h = (lane >> 4) & 1;
    const int j = lane & 15;
    const int c = 16 * h + j;                    // dword-pair index 0..31
    const int d0 = blockIdx.x * 16 + wv * 4;     // 12500 blocks, exact
    const float sAB = p_rel_AB[h] * 0.125f;
    const float sBA = p_rel_BA[h] * 0.125f;

    for (int r = 0; r < 4; ++r) {
        const int d = d0 + r;
        const uint2 q2 = *reinterpret_cast<const uint2*>(qb + (long)d * 64 + 2 * c);
        float av0 = 0.f, av1 = 0.f, av2 = 0.f, av3 = 0.f;
        float ae00 = 0.f, ae01 = 0.f, ae10 = 0.f, ae11 = 0.f;
        float den = 0.f;
        const int beg = offsets[d], end = offsets[d + 1];
        for (int p0 = beg; p0 < end; p0 += 2) {
            const int p = p0 + eh;
            const bool valid = (p < end);
            const int pc = valid ? p : p0;
            const int src = csr_src[pc];
            const int ee = csr_ee[pc];
            const uint4 kvd = kv[(long)src * 32 + c];
            float partial = fmaf(bf_lo(q2.x), bf_lo(kvd.x),
                            fmaf(bf_hi(q2.x), bf_hi(kvd.x),
                            fmaf(bf_lo(q2.y), bf_lo(kvd.z),
                                 bf_hi(q2.y) * bf_hi(kvd.z))));
            partial += __shfl_xor(partial, 1);
            partial += __shfl_xor(partial, 2);
            partial += __shfl_xor(partial, 4);
            partial += __shfl_xor(partial, 8);
            const float s = (ee < EE) ? sAB : sBA;
            float e = valid ? expf(partial * s) : 0.f;
            const unsigned efd = ef[(long)ee * 32 + c];
            const float ef0 = bf_lo(efd), ef1 = bf_hi(efd);
            const float e_oth = __shfl_xor(e, 16);
            const float w0 = h ? e_oth : e;      // head-0 softmax weight
            const float w1 = h ? e : e_oth;      // head-1 softmax weight
            av0 = fmaf(e, bf_lo(kvd.y), av0);
            av1 = fmaf(e, bf_hi(kvd.y), av1);
            av2 = fmaf(e, bf_lo(kvd.w), av2);
            av3 = fmaf(e, bf_hi(kvd.w), av3);
            ae00 = fmaf(w0, ef0, ae00);
            ae01 = fmaf(w0, ef1, ae01);
            ae10 = fmaf(w1, ef0, ae10);
            ae11 = fmaf(w1, ef1, ae11);
            den += e;
        }
        // merge the two edge-slot halves
        av0 += __shfl_xor(av0, 32);
        av1 += __shfl_xor(av1, 32);
        av2 += __shfl_xor(av2, 32);
        av3 += __shfl_xor(av3, 32);
        ae00 += __shfl_xor(ae00, 32);
        ae01 += __shfl_xor(ae01, 32);
        ae10 += __shfl_xor(ae10, 32);
        ae11 += __shfl_xor(ae11, 32);
        den += __shfl_xor(den, 32);

        const float inv = 1.f / (den + 1e-16f);          // own head's inverse denom
        const float inv_oth = __shfl_xor(inv, 16);
        const float inv0 = h ? inv_oth : inv;
        const float inv1 = h ? inv : inv_oth;

        if (eh == 0) {
            const float gv0 = gelu_exact(av0 * inv);
            const float gv1 = gelu_exact(av1 * inv);
            const float gv2 = gelu_exact(av2 * inv);
            const float gv3 = gelu_exact(av3 * inv);
            const float ge00 = gelu_exact(ae00 * inv0);
            const float ge01 = gelu_exact(ae01 * inv0);
            const float ge10 = gelu_exact(ae10 * inv1);
            const float ge11 = gelu_exact(ae11 * inv1);
            unsigned* gp = g + (long)d * 128;
            const int vb = h ? (64 + 2 * j) : (2 * j);   // v block dword base
            gp[vb]     = pack_bf2(gv0, gv1);
            gp[vb + 1] = pack_bf2(gv2, gv3);
            gp[32 + c] = pack_bf2(ge00, ge01);           // ef, head-0 block
            gp[96 + c] = pack_bf2(ge10, ge11);           // ef, head-1 block
        }
    }
}

// ---------- K4: MFMA out-projection (A and B in one grid), in-place over g ----------
__global__ __launch_bounds__(256) void proj_mfma_kernel(
    const short* __restrict__ g,
    const float* __restrict__ W_out_A, const float* __restrict__ b_out_A,
    const float* __restrict__ W_out_B, const float* __restrict__ b_out_B,
    const float* __restrict__ x_A, const float* __restrict__ x_B,
    const float* __restrict__ skip_A, const float* __restrict__ skip_B,
    float* __restrict__ out, int nblkA)
{
    const bool isA = ((int)blockIdx.x < nblkA);
    const int blk = isA ? blockIdx.x : (blockIdx.x - nblkA);
    const float* __restrict__ W_out = isA ? W_out_A : W_out_B;
    const float* __restrict__ b_out = isA ? b_out_A : b_out_B;
    const float* __restrict__ x = isA ? x_A : x_B;
    const float* __restrict__ skip = isA ? skip_A : skip_B;
    const int roff = isA ? 0 : NA;
    const int N = isA ? NA : NB;

    __shared__ unsigned short Wt[128 * 264];
    const int tid = threadIdx.x;
    const int lane = tid & 63;
    const int wv = tid >> 6;

    for (int idx = tid; idx < 256 * 128; idx += 256) {
        const int k = idx >> 7, n = idx & 127;
        Wt[n * 264 + k] = (unsigned short)bf16rne(W_out[idx]);
    }
    __syncthreads();

    const int m0 = roff + blk * 64 + wv * 16;
    const int rmax = roff + N - 1;
    const float ag = 1.f / (1.f + expf(-skip[0]));

    f32x4 acc[8];
    #pragma unroll
    for (int nf = 0; nf < 8; ++nf) acc[nf] = (f32x4){0.f, 0.f, 0.f, 0.f};

    const int arow = min(m0 + (lane & 15), rmax);
    const int kgrp = (lane >> 4) * 8;

    #pragma unroll
    for (int ks = 0; ks < 8; ++ks) {
        const bf16x8 a = *reinterpret_cast<const bf16x8*>(g + (long)arow * 256 + ks * 32 + kgrp);
        #pragma unroll
        for (int nf = 0; nf < 8; ++nf) {
            const bf16x8 b = *reinterpret_cast<const bf16x8*>(&Wt[(nf * 16 + (lane & 15)) * 264 + ks * 32 + kgrp]);
            acc[nf] = __builtin_amdgcn_mfma_f32_16x16x32_bf16(a, b, acc[nf], 0, 0, 0);
        }
    }

    #pragma unroll
    for (int nf = 0; nf < 8; ++nf) {
        const int col = nf * 16 + (lane & 15);
        const float bc = b_out[col];
        #pragma unroll
        for (int reg = 0; reg < 4; ++reg) {
            const int d = m0 + (lane >> 4) * 4 + reg;
            if (d <= rmax) {
                const float xv = x[(long)(d - roff) * 128 + col];
                out[(long)d * 128 + col] = fmaf(ag, acc[nf][reg] + bc, (1.f - ag) * xv);
            }
        }
    }
}

// ---------- launcher ----------
extern "C" void kernel_launch(void* const* d_in, const int* in_sizes, int n_in,
                              void* d_out, int out_size, void* d_ws, size_t ws_size,
                              hipStream_t stream) {
    const float* x_A     = (const float*)d_in[0];
    const float* x_B     = (const float*)d_in[1];
    const float* lu_A    = (const float*)d_in[2];
    const float* lu_B    = (const float*)d_in[3];
    const float* t_AB    = (const float*)d_in[4];
    const float* t_BA    = (const float*)d_in[5];
    const float* msg_AB  = (const float*)d_in[6];
    const float* msg_BA  = (const float*)d_in[7];
    const float* W_kqv_A = (const float*)d_in[8];
    const float* b_kqv_A = (const float*)d_in[9];
    const float* W_kqv_B = (const float*)d_in[10];
    const float* b_kqv_B = (const float*)d_in[11];
    const float* Wk_rel  = (const float*)d_in[12];
    const float* Wv_rel  = (const float*)d_in[13];
    const float* W_edge  = (const float*)d_in[14];
    const float* b_edge  = (const float*)d_in[15];
    const float* W_out_A = (const float*)d_in[16];
    const float* b_out_A = (const float*)d_in[17];
    const float* W_out_B = (const float*)d_in[18];
    const float* b_out_B = (const float*)d_in[19];
    const float* skip_A  = (const float*)d_in[20];
    const float* skip_B  = (const float*)d_in[21];
    const float* p_rel_AB= (const float*)d_in[22];
    const float* p_rel_BA= (const float*)d_in[23];
    const float* time_w  = (const float*)d_in[24];
    const float* time_b  = (const float*)d_in[25];
    const int*   eiAB    = (const int*)d_in[26];
    const int*   eiBA    = (const int*)d_in[27];
    float* out = (float*)d_out;

    // workspace layout (~264 MB)
    unsigned* q_bf  = (unsigned*)d_ws;                  // 12.8M u32
    unsigned* kvbuf = q_bf + 12800000;                  // 25.6M u32
    unsigned* efbuf = kvbuf + 25600000;                 // 25.6M u32
    int* cnt      = (int*)(efbuf + 25600000);           // 200000
    int* offsets  = cnt + 200000;                       // 210000
    int* csr_src  = offsets + 210000;                   // 800000
    int* csr_ee   = csr_src + 800000;                   // 800000
    unsigned short* WfA = (unsigned short*)(csr_ee + 800000);  // 49152 bf16
    unsigned short* WfB = WfA + 49152;                  // 49152 bf16
    float* bfA    = (float*)(WfB + 49152);              // 384
    float* bfB    = bfA + 384;                          // 384
    int* bsum     = (int*)(bfB + 384);                  // 256
    int* bbase    = bsum + 256;                         // 256
    unsigned short* Wet = (unsigned short*)(bbase + 256); // 12288 bf16

    (void)hipMemsetAsync(cnt, 0, (size_t)200000 * 4, stream);

    // CSR build
    count_kernel<<<(2 * EE + 255) / 256, 256, 0, stream>>>(eiAB, eiBA, cnt);
    scan1_kernel<<<196, 1024, 0, stream>>>(cnt, offsets, bsum);
    scan2_kernel<<<1, 256, 0, stream>>>(bsum, bbase, 196);
    scan3_kernel<<<196, 1024, 0, stream>>>(offsets, bbase, cnt);
    fill_kernel<<<(2 * EE + 255) / 256, 256, 0, stream>>>(eiAB, eiBA, cnt, csr_src, csr_ee);

    // weight prep
    fusew_kernel<<<768, 128, 0, stream>>>(W_kqv_A, b_kqv_A, W_kqv_B, b_kqv_B,
                                          Wk_rel, Wv_rel, WfA, bfA, WfB, bfB);
    wedget_kernel<<<64, 192, 0, stream>>>(W_edge, Wet);

    // MFMA kqv (A+B)
    const int nblkA = (NA + BM - 1) / BM;
    const int nblkB = (NB + BM - 1) / BM;
    kqv_mfma_kernel<<<nblkA + nblkB, 256, 0, stream>>>(x_A, x_B, WfA, WfB, bfA, bfB,
                                                       q_bf, kvbuf, nblkA);

    // edge features, wave-synchronous (AB+BA): 50000 wave-tiles / 4 per block
    edgefeat_wave_kernel<<<12500, 256, 0, stream>>>(lu_A, lu_B, eiAB, eiBA,
                                                    t_AB, t_BA, msg_AB, msg_BA,
                                                    time_w, time_b, Wet, b_edge, efbuf);

    gather_kernel<<<NTOT / 16, 256, 0, stream>>>(q_bf, (const uint4*)kvbuf, efbuf,
                                                 offsets, csr_src, csr_ee,
                                                 p_rel_AB, p_rel_BA, (unsigned*)out);

    // MFMA out-projection (A+B)
    proj_mfma_kernel<<<2 * 1563, 256, 0, stream>>>((const short*)out,
                                                   W_out_A, b_out_A, W_out_B, b_out_B,
                                                   x_A, x_B, skip_A, skip_B, out, 1563);
}

// Round 10
// 779.067 us; speedup vs baseline: 3.0653x; 1.0323x over previous
//
#include <hip/hip_runtime.h>
#include <math.h>

#define NA 100000
#define NB 100000
#define NTOT 200000
#define EE 400000      // edges per type
#define TDIM 100       // time encoder dim
#define NTILE (EE / 16)

typedef short bf16x8 __attribute__((ext_vector_type(8)));
typedef float f32x4 __attribute__((ext_vector_type(4)));

// ---------- helpers ----------
__device__ __forceinline__ float gelu_exact(float x) {
    return 0.5f * x * (1.0f + erff(x * 0.70710678118654752f));
}
__device__ __forceinline__ unsigned bf16rne(float f) {
    unsigned u = __float_as_uint(f);
    return (u + 0x7fffu + ((u >> 16) & 1u)) >> 16;
}
__device__ __forceinline__ unsigned pack_bf2(float lo, float hi) {
    return bf16rne(lo) | (bf16rne(hi) << 16);
}
__device__ __forceinline__ float bf_lo(unsigned u) { return __uint_as_float(u << 16); }
__device__ __forceinline__ float bf_hi(unsigned u) { return __uint_as_float(u & 0xffff0000u); }

// ---------- K0: fuse rel-transform into kqv weights (A and B in one grid) ----------
__global__ __launch_bounds__(128) void fusew_kernel(
    const float* __restrict__ W_A, const float* __restrict__ b_A,
    const float* __restrict__ W_B, const float* __restrict__ b_B,
    const float* __restrict__ Wk_rel, const float* __restrict__ Wv_rel,
    unsigned short* __restrict__ WfA, float* __restrict__ bfA,
    unsigned short* __restrict__ WfB, float* __restrict__ bfB)
{
    const int et = (blockIdx.x >= 384) ? 1 : 0;
    const int c = blockIdx.x - et * 384;       // 0..383
    const int i = threadIdx.x;                 // 0..127
    const float* __restrict__ W = et ? W_B : W_A;
    const float* __restrict__ b = et ? b_B : b_A;
    unsigned short* __restrict__ Wf_t = et ? WfB : WfA;
    float* __restrict__ bf = et ? bfB : bfA;

    float acc = 0.f;
    if (c < 128) {
        const int h = c >> 6, e = c & 63;
        const float* __restrict__ Wr = Wk_rel + (long)(h * 2 + et) * 4096;
        for (int d = 0; d < 64; ++d) acc += W[i * 384 + h * 64 + d] * Wr[d * 64 + e];
    } else if (c < 256) {
        acc = W[i * 384 + c];
    } else {
        const int h = (c - 256) >> 6, e = (c - 256) & 63;
        const float* __restrict__ Wr = Wv_rel + (long)(h * 2 + et) * 4096;
        for (int d = 0; d < 64; ++d) acc += W[i * 384 + 256 + h * 64 + d] * Wr[d * 64 + e];
    }
    Wf_t[c * 128 + i] = (unsigned short)bf16rne(acc);
    if (i == 0) {
        float bacc = 0.f;
        if (c < 128) {
            const int h = c >> 6, e = c & 63;
            const float* __restrict__ Wr = Wk_rel + (long)(h * 2 + et) * 4096;
            for (int d = 0; d < 64; ++d) bacc += b[h * 64 + d] * Wr[d * 64 + e];
        } else if (c < 256) {
            bacc = b[c];
        } else {
            const int h = (c - 256) >> 6, e = (c - 256) & 63;
            const float* __restrict__ Wr = Wv_rel + (long)(h * 2 + et) * 4096;
            for (int d = 0; d < 64; ++d) bacc += b[256 + h * 64 + d] * Wr[d * 64 + e];
        }
        bf[c] = bacc;
    }
}

// ---------- K0b: W_edge^T -> bf16 [64][192] (k padded 164->192) ----------
__global__ __launch_bounds__(192) void wedget_kernel(
    const float* __restrict__ W_edge, unsigned short* __restrict__ Wt)
{
    const int col = blockIdx.x;      // 0..63
    const int k = threadIdx.x;       // 0..191
    const float v = (k < 164) ? W_edge[k * 64 + col] : 0.f;
    Wt[col * 192 + k] = (unsigned short)bf16rne(v);
}

// ---------- K1: kqv MFMA GEMM (A and B in one grid), LDS-staged coalesced stores ----------
#define BM 32
__global__ __launch_bounds__(256) void kqv_mfma_kernel(
    const float* __restrict__ x_A, const float* __restrict__ x_B,
    const unsigned short* __restrict__ WfA, const unsigned short* __restrict__ WfB,
    const float* __restrict__ bfA, const float* __restrict__ bfB,
    unsigned* __restrict__ q_u32, unsigned* __restrict__ kv_u32, int nblkA)
{
    const bool isA = ((int)blockIdx.x < nblkA);
    const int blk = isA ? blockIdx.x : (blockIdx.x - nblkA);
    const float* __restrict__ x = isA ? x_A : x_B;
    const unsigned short* __restrict__ Wf_t = isA ? WfA : WfB;
    const float* __restrict__ bf = isA ? bfA : bfB;
    const int node_off = isA ? 0 : NA;

    __shared__ unsigned xs[BM][68];              // pair-packed bf16 input tile
    __shared__ unsigned st[BM][200];             // output staging: [node][dword], row = 192 + pad
    const int tid = threadIdx.x;
    const int lane = tid & 63;
    const int wv = tid >> 6;
    const int m = lane & 15;
    const int kq = lane >> 4;                    // k-group 0..3
    const int n0 = blk * BM;                     // NA % 32 == 0: no guards anywhere

    for (int idx = tid; idx < BM * 64; idx += 256) {
        const int n = idx >> 6, j = idx & 63;
        const float2 xv = *reinterpret_cast<const float2*>(x + (long)(n0 + n) * 128 + 2 * j);
        xs[n][j] = pack_bf2(xv.x, xv.y);
    }
    __syncthreads();

    const int wq = wv * 96;                      // this wave's col base
    f32x4 acc[2][6];
    #pragma unroll
    for (int mt = 0; mt < 2; ++mt)
        #pragma unroll
        for (int nt = 0; nt < 6; ++nt) acc[mt][nt] = (f32x4){0.f, 0.f, 0.f, 0.f};

    #pragma unroll
    for (int ks = 0; ks < 4; ++ks) {
        bf16x8 a[2], bfr[6];
        #pragma unroll
        for (int mt = 0; mt < 2; ++mt)
            a[mt] = *reinterpret_cast<const bf16x8*>(&xs[mt * 16 + m][ks * 16 + kq * 4]);
        #pragma unroll
        for (int nt = 0; nt < 6; ++nt) {
            const int col = wq + nt * 16 + m;
            bfr[nt] = *reinterpret_cast<const bf16x8*>(Wf_t + (long)col * 128 + ks * 32 + kq * 8);
        }
        #pragma unroll
        for (int mt = 0; mt < 2; ++mt)
            #pragma unroll
            for (int nt = 0; nt < 6; ++nt)
                acc[mt][nt] = __builtin_amdgcn_mfma_f32_16x16x32_bf16(a[mt], bfr[nt], acc[mt][nt], 0, 0, 0);
    }

    // epilogue: +bias, pair-exchange, even lanes write packed dwords into st[node][dw]
    // row layout == global: dw 0..127 = kv row (even=k-pair, odd=v-pair), 128..191 = q row
    #pragma unroll
    for (int nt = 0; nt < 6; ++nt) {
        const int c = wq + nt * 16 + m;
        const float bias_c = bf[c];
        int dw;
        if (c < 128)      dw = c;                        // k-pair at even dword c
        else if (c < 256) dw = 128 + ((c - 128) >> 1);   // q
        else              dw = (c - 256) + 1;            // v-pair at odd dword
        #pragma unroll
        for (int mt = 0; mt < 2; ++mt) {
            #pragma unroll
            for (int reg = 0; reg < 4; ++reg) {
                const float v = acc[mt][nt][reg] + bias_c;
                const float o = __shfl_xor(v, 1);
                if (!(m & 1)) st[mt * 16 + kq * 4 + reg][dw] = pack_bf2(v, o);
            }
        }
    }
    __syncthreads();

    // cooperative fully-coalesced store: 8 threads per node
    {
        const int n = tid >> 3;
        const long nb = node_off + n0 + n;
        const int d0 = (tid & 7) * 16;
        #pragma unroll
        for (int i = 0; i < 4; ++i) {
            uint4 w;
            w.x = st[n][d0 + i * 4 + 0];
            w.y = st[n][d0 + i * 4 + 1];
            w.z = st[n][d0 + i * 4 + 2];
            w.w = st[n][d0 + i * 4 + 3];
            *reinterpret_cast<uint4*>(kv_u32 + nb * 128 + d0 + i * 4) = w;
        }
        const int dq = (tid & 7) * 8;
        #pragma unroll
        for (int i = 0; i < 2; ++i) {
            uint4 w;
            w.x = st[n][128 + dq + i * 4 + 0];
            w.y = st[n][128 + dq + i * 4 + 1];
            w.z = st[n][128 + dq + i * 4 + 2];
            w.w = st[n][128 + dq + i * 4 + 3];
            *reinterpret_cast<uint4*>(q_u32 + nb * 64 + dq + i * 4) = w;
        }
    }
}

// ---------- K2: edge_feat, wave-synchronous: one wave = 16 edges, no barriers ----------
__global__ __launch_bounds__(256) void edgefeat_wave_kernel(
    const float* __restrict__ lu_A, const float* __restrict__ lu_B,
    const int* __restrict__ eiAB, const int* __restrict__ eiBA,
    const float* __restrict__ t_AB, const float* __restrict__ t_BA,
    const float* __restrict__ msg_AB, const float* __restrict__ msg_BA,
    const float* __restrict__ time_w, const float* __restrict__ time_b,
    const unsigned short* __restrict__ Wt, const float* __restrict__ b_edge,
    unsigned* __restrict__ ef_u32)
{
    __shared__ unsigned feat[4][16][100];        // per-wave 6.4KB slab, K=192 bf16 in dwords 0..95
    const int tid = threadIdx.x;
    const int lane = tid & 63;
    const int wv = tid >> 6;
    const int gw = blockIdx.x * 4 + wv;          // 0..49999
    const bool isAB = gw < NTILE;
    const int tile = isAB ? gw : gw - NTILE;
    const float* __restrict__ lu   = isAB ? lu_A : lu_B;
    const int* __restrict__ ei     = isAB ? eiAB : eiBA;
    const float* __restrict__ tvec = isAB ? t_AB : t_BA;
    const float* __restrict__ msg  = isAB ? msg_AB : msg_BA;
    const long out_off = isAB ? 0L : (long)EE;
    const long e0 = (long)tile * 16;

    unsigned (* __restrict__ fw)[100] = feat[wv];

    // edge meta in lanes 0..15 (random lu gather issued first)
    float rts_l = 0.f;
    if (lane < 16) rts_l = lu[ei[e0 + lane]] - tvec[e0 + lane];

    // msg staging: lane -> edge e = lane>>2, quarter qt = lane&3 (16 floats -> 8 dwords)
    {
        const int e = lane >> 2, qt = lane & 3;
        const float* mp = msg + (e0 + e) * 64 + qt * 16;
        const float4 a0 = *reinterpret_cast<const float4*>(mp);
        const float4 a1 = *reinterpret_cast<const float4*>(mp + 4);
        const float4 a2 = *reinterpret_cast<const float4*>(mp + 8);
        const float4 a3 = *reinterpret_cast<const float4*>(mp + 12);
        uint2 w0, w1, w2, w3;
        w0.x = pack_bf2(a0.x, a0.y); w0.y = pack_bf2(a0.z, a0.w);
        w1.x = pack_bf2(a1.x, a1.y); w1.y = pack_bf2(a1.z, a1.w);
        w2.x = pack_bf2(a2.x, a2.y); w2.y = pack_bf2(a2.z, a2.w);
        w3.x = pack_bf2(a3.x, a3.y); w3.y = pack_bf2(a3.z, a3.w);
        *reinterpret_cast<uint2*>(&fw[e][50 + qt * 8])     = w0;
        *reinterpret_cast<uint2*>(&fw[e][50 + qt * 8 + 2]) = w1;
        *reinterpret_cast<uint2*>(&fw[e][50 + qt * 8 + 4]) = w2;
        *reinterpret_cast<uint2*>(&fw[e][50 + qt * 8 + 6]) = w3;
    }
    // time-encoding: 16 edges x 50 dwords = 800 dwords
    #pragma unroll
    for (int i = 0; i < 13; ++i) {
        const int idx = lane + (i << 6);
        if (idx < 800) {
            const int e = idx / 50, j = idx - e * 50;
            const float r = __shfl(rts_l, e);
            const float c0 = __cosf(fmaf(r, time_w[2 * j], time_b[2 * j]));
            const float c1 = __cosf(fmaf(r, time_w[2 * j + 1], time_b[2 * j + 1]));
            fw[e][j] = pack_bf2(c0, c1);
        }
    }
    // zero pad: dwords 82..99 per edge (K 164->192 bf16 + row tail)
    #pragma unroll
    for (int i = 0; i < 5; ++i) {
        const int idx = lane + (i << 6);
        if (idx < 288) {
            const int e = idx / 18, j = idx - e * 18;
            fw[e][82 + j] = 0u;
        }
    }
    // wave-local LDS write->read ordering (no __syncthreads needed)
    asm volatile("s_waitcnt lgkmcnt(0)" ::: "memory");

    const int m = lane & 15;
    const int kq = lane >> 4;
    f32x4 acc[4];
    #pragma unroll
    for (int nf = 0; nf < 4; ++nf) acc[nf] = (f32x4){0.f, 0.f, 0.f, 0.f};

    #pragma unroll
    for (int ks = 0; ks < 6; ++ks) {
        const bf16x8 a = *reinterpret_cast<const bf16x8*>(&fw[m][ks * 16 + kq * 4]);
        #pragma unroll
        for (int nf = 0; nf < 4; ++nf) {
            const bf16x8 b = *reinterpret_cast<const bf16x8*>(Wt + (long)(nf * 16 + m) * 192 + ks * 32 + kq * 8);
            acc[nf] = __builtin_amdgcn_mfma_f32_16x16x32_bf16(a, b, acc[nf], 0, 0, 0);
        }
    }

    #pragma unroll
    for (int nf = 0; nf < 4; ++nf) {
        const int c = nf * 16 + m;
        const float bc = b_edge[c];
        #pragma unroll
        for (int reg = 0; reg < 4; ++reg) {
            const float v = acc[nf][reg] + bc;
            const float o = __shfl_xor(v, 1);
            if (!(lane & 1)) {
                const long ee = out_off + e0 + kq * 4 + reg;
                ef_u32[ee * 32 + (c >> 1)] = pack_bf2(v, o);
            }
        }
    }
}

// ---------- CSR build ----------
__global__ __launch_bounds__(256) void count_kernel(
    const int* __restrict__ eiAB, const int* __restrict__ eiBA, int* __restrict__ cnt)
{
    const int ee = blockIdx.x * 256 + threadIdx.x;
    if (ee >= 2 * EE) return;
    const int dst = (ee < EE) ? (eiAB[EE + ee] + NA) : eiBA[EE + (ee - EE)];
    atomicAdd(&cnt[dst], 1);
}

__global__ __launch_bounds__(1024) void scan1_kernel(
    const int* __restrict__ cnt, int* __restrict__ offsets, int* __restrict__ bsum)
{
    __shared__ int tmp[1024];
    const int t = threadIdx.x;
    const int i = blockIdx.x * 1024 + t;
    const int v = (i < NTOT) ? cnt[i] : 0;
    tmp[t] = v;
    __syncthreads();
    for (int off = 1; off < 1024; off <<= 1) {
        const int u = (t >= off) ? tmp[t - off] : 0;
        __syncthreads();
        tmp[t] += u;
        __syncthreads();
    }
    offsets[i] = tmp[t] - v;
    if (t == 1023) bsum[blockIdx.x] = tmp[1023];
}

__global__ __launch_bounds__(256) void scan2_kernel(
    const int* __restrict__ bsum, int* __restrict__ bbase, int nblk)
{
    __shared__ int tmp[256];
    const int t = threadIdx.x;
    const int v = (t < nblk) ? bsum[t] : 0;
    tmp[t] = v;
    __syncthreads();
    for (int off = 1; off < 256; off <<= 1) {
        const int u = (t >= off) ? tmp[t - off] : 0;
        __syncthreads();
        tmp[t] += u;
        __syncthreads();
    }
    bbase[t] = tmp[t] - v;
}

__global__ __launch_bounds__(1024) void scan3_kernel(
    int* __restrict__ offsets, const int* __restrict__ bbase, int* __restrict__ cnt)
{
    const int t = threadIdx.x;
    const int i = blockIdx.x * 1024 + t;
    const int o = offsets[i] + bbase[blockIdx.x];
    offsets[i] = o;
    if (i < NTOT) cnt[i] = o;
    if (blockIdx.x == 0 && t == 0) offsets[NTOT] = 2 * EE;
}

__global__ __launch_bounds__(256) void fill_kernel(
    const int* __restrict__ eiAB, const int* __restrict__ eiBA,
    int* __restrict__ cursor, int* __restrict__ csr_src, int* __restrict__ csr_ee)
{
    const int ee = blockIdx.x * 256 + threadIdx.x;
    if (ee >= 2 * EE) return;
    int src, dst;
    if (ee < EE) { src = eiAB[ee];               dst = eiAB[EE + ee] + NA; }
    else { const int e = ee - EE; src = eiBA[e] + NA; dst = eiBA[EE + e]; }
    const int pos = atomicAdd(&cursor[dst], 1);
    csr_src[pos] = src;
    csr_ee[pos] = ee;
}

// ---------- K3: fused flash-softmax gather + gelu, 2 edges per wave ----------
// lane = 32*eh + 16*h + j : eh = edge slot, h = head, j = comp group (4 comps)
__global__ __launch_bounds__(256) void gather_kernel(
    const unsigned* __restrict__ qb, const uint4* __restrict__ kv,
    const unsigned* __restrict__ ef,
    const int* __restrict__ offsets, const int* __restrict__ csr_src, const int* __restrict__ csr_ee,
    const float* __restrict__ p_rel_AB, const float* __restrict__ p_rel_BA,
    unsigned* __restrict__ g)
{
    const int lane = threadIdx.x & 63;
    const int wv = threadIdx.x >> 6;
    const int eh = lane >> 5;
    const int h = (lane >> 4) & 1;
    const int j = lane & 15;
    const int c = 16 * h + j;                    // dword-pair index 0..31
    const int d0 = blockIdx.x * 16 + wv * 4;     // 12500 blocks, exact
    const float sAB = p_rel_AB[h] * 0.125f;
    const float sBA = p_rel_BA[h] * 0.125f;

    for (int r = 0; r < 4; ++r) {
        const int d = d0 + r;
        const uint2 q2 = *reinterpret_cast<const uint2*>(qb + (long)d * 64 + 2 * c);
        float av0 = 0.f, av1 = 0.f, av2 = 0.f, av3 = 0.f;
        float ae00 = 0.f, ae01 = 0.f, ae10 = 0.f, ae11 = 0.f;
        float den = 0.f;
        const int beg = offsets[d], end = offsets[d + 1];
        for (int p0 = beg; p0 < end; p0 += 2) {
            const int p = p0 + eh;
            const bool valid = (p < end);
            const int pc = valid ? p : p0;
            const int src = csr_src[pc];
            const int ee = csr_ee[pc];
            const uint4 kvd = kv[(long)src * 32 + c];
            float partial = fmaf(bf_lo(q2.x), bf_lo(kvd.x),
                            fmaf(bf_hi(q2.x), bf_hi(kvd.x),
                            fmaf(bf_lo(q2.y), bf_lo(kvd.z),
                                 bf_hi(q2.y) * bf_hi(kvd.z))));
            partial += __shfl_xor(partial, 1);
            partial += __shfl_xor(partial, 2);
            partial += __shfl_xor(partial, 4);
            partial += __shfl_xor(partial, 8);
            const float s = (ee < EE) ? sAB : sBA;
            float e = valid ? expf(partial * s) : 0.f;
            const unsigned efd = ef[(long)ee * 32 + c];
            const float ef0 = bf_lo(efd), ef1 = bf_hi(efd);
            const float e_oth = __shfl_xor(e, 16);
            const float w0 = h ? e_oth : e;      // head-0 softmax weight
            const float w1 = h ? e : e_oth;      // head-1 softmax weight
            av0 = fmaf(e, bf_lo(kvd.y), av0);
            av1 = fmaf(e, bf_hi(kvd.y), av1);
            av2 = fmaf(e, bf_lo(kvd.w), av2);
            av3 = fmaf(e, bf_hi(kvd.w), av3);
            ae00 = fmaf(w0, ef0, ae00);
            ae01 = fmaf(w0, ef1, ae01);
            ae10 = fmaf(w1, ef0, ae10);
            ae11 = fmaf(w1, ef1, ae11);
            den += e;
        }
        // merge the two edge-slot halves
        av0 += __shfl_xor(av0, 32);
        av1 += __shfl_xor(av1, 32);
        av2 += __shfl_xor(av2, 32);
        av3 += __shfl_xor(av3, 32);
        ae00 += __shfl_xor(ae00, 32);
        ae01 += __shfl_xor(ae01, 32);
        ae10 += __shfl_xor(ae10, 32);
        ae11 += __shfl_xor(ae11, 32);
        den += __shfl_xor(den, 32);

        const float inv = 1.f / (den + 1e-16f);          // own head's inverse denom
        const float inv_oth = __shfl_xor(inv, 16);
        const float inv0 = h ? inv_oth : inv;
        const float inv1 = h ? inv : inv_oth;

        if (eh == 0) {
            const float gv0 = gelu_exact(av0 * inv);
            const float gv1 = gelu_exact(av1 * inv);
            const float gv2 = gelu_exact(av2 * inv);
            const float gv3 = gelu_exact(av3 * inv);
            const float ge00 = gelu_exact(ae00 * inv0);
            const float ge01 = gelu_exact(ae01 * inv0);
            const float ge10 = gelu_exact(ae10 * inv1);
            const float ge11 = gelu_exact(ae11 * inv1);
            unsigned* gp = g + (long)d * 128;
            const int vb = h ? (64 + 2 * j) : (2 * j);   // v block dword base
            gp[vb]     = pack_bf2(gv0, gv1);
            gp[vb + 1] = pack_bf2(gv2, gv3);
            gp[32 + c] = pack_bf2(ge00, ge01);           // ef, head-0 block
            gp[96 + c] = pack_bf2(ge10, ge11);           // ef, head-1 block
        }
    }
}

// ---------- K4: MFMA out-projection (A and B in one grid), in-place over g ----------
__global__ __launch_bounds__(256) void proj_mfma_kernel(
    const short* __restrict__ g,
    const float* __restrict__ W_out_A, const float* __restrict__ b_out_A,
    const float* __restrict__ W_out_B, const float* __restrict__ b_out_B,
    const float* __restrict__ x_A, const float* __restrict__ x_B,
    const float* __restrict__ skip_A, const float* __restrict__ skip_B,
    float* __restrict__ out, int nblkA)
{
    const bool isA = ((int)blockIdx.x < nblkA);
    const int blk = isA ? blockIdx.x : (blockIdx.x - nblkA);
    const float* __restrict__ W_out = isA ? W_out_A : W_out_B;
    const float* __restrict__ b_out = isA ? b_out_A : b_out_B;
    const float* __restrict__ x = isA ? x_A : x_B;
    const float* __restrict__ skip = isA ? skip_A : skip_B;
    const int roff = isA ? 0 : NA;
    const int N = isA ? NA : NB;

    __shared__ unsigned short Wt[128 * 264];
    const int tid = threadIdx.x;
    const int lane = tid & 63;
    const int wv = tid >> 6;

    for (int idx = tid; idx < 256 * 128; idx += 256) {
        const int k = idx >> 7, n = idx & 127;
        Wt[n * 264 + k] = (unsigned short)bf16rne(W_out[idx]);
    }
    __syncthreads();

    const int m0 = roff + blk * 64 + wv * 16;
    const int rmax = roff + N - 1;
    const float ag = 1.f / (1.f + expf(-skip[0]));

    f32x4 acc[8];
    #pragma unroll
    for (int nf = 0; nf < 8; ++nf) acc[nf] = (f32x4){0.f, 0.f, 0.f, 0.f};

    const int arow = min(m0 + (lane & 15), rmax);
    const int kgrp = (lane >> 4) * 8;

    #pragma unroll
    for (int ks = 0; ks < 8; ++ks) {
        const bf16x8 a = *reinterpret_cast<const bf16x8*>(g + (long)arow * 256 + ks * 32 + kgrp);
        #pragma unroll
        for (int nf = 0; nf < 8; ++nf) {
            const bf16x8 b = *reinterpret_cast<const bf16x8*>(&Wt[(nf * 16 + (lane & 15)) * 264 + ks * 32 + kgrp]);
            acc[nf] = __builtin_amdgcn_mfma_f32_16x16x32_bf16(a, b, acc[nf], 0, 0, 0);
        }
    }

    #pragma unroll
    for (int nf = 0; nf < 8; ++nf) {
        const int col = nf * 16 + (lane & 15);
        const float bc = b_out[col];
        #pragma unroll
        for (int reg = 0; reg < 4; ++reg) {
            const int d = m0 + (lane >> 4) * 4 + reg;
            if (d <= rmax) {
                const float xv = x[(long)(d - roff) * 128 + col];
                out[(long)d * 128 + col] = fmaf(ag, acc[nf][reg] + bc, (1.f - ag) * xv);
            }
        }
    }
}

// ---------- launcher ----------
extern "C" void kernel_launch(void* const* d_in, const int* in_sizes, int n_in,
                              void* d_out, int out_size, void* d_ws, size_t ws_size,
                              hipStream_t stream) {
    const float* x_A     = (const float*)d_in[0];
    const float* x_B     = (const float*)d_in[1];
    const float* lu_A    = (const float*)d_in[2];
    const float* lu_B    = (const float*)d_in[3];
    const float* t_AB    = (const float*)d_in[4];
    const float* t_BA    = (const float*)d_in[5];
    const float* msg_AB  = (const float*)d_in[6];
    const float* msg_BA  = (const float*)d_in[7];
    const float* W_kqv_A = (const float*)d_in[8];
    const float* b_kqv_A = (const float*)d_in[9];
    const float* W_kqv_B = (const float*)d_in[10];
    const float* b_kqv_B = (const float*)d_in[11];
    const float* Wk_rel  = (const float*)d_in[12];
    const float* Wv_rel  = (const float*)d_in[13];
    const float* W_edge  = (const float*)d_in[14];
    const float* b_edge  = (const float*)d_in[15];
    const float* W_out_A = (const float*)d_in[16];
    const float* b_out_A = (const float*)d_in[17];
    const float* W_out_B = (const float*)d_in[18];
    const float* b_out_B = (const float*)d_in[19];
    const float* skip_A  = (const float*)d_in[20];
    const float* skip_B  = (const float*)d_in[21];
    const float* p_rel_AB= (const float*)d_in[22];
    const float* p_rel_BA= (const float*)d_in[23];
    const float* time_w  = (const float*)d_in[24];
    const float* time_b  = (const float*)d_in[25];
    const int*   eiAB    = (const int*)d_in[26];
    const int*   eiBA    = (const int*)d_in[27];
    float* out = (float*)d_out;

    // workspace layout (~264 MB)
    unsigned* q_bf  = (unsigned*)d_ws;                  // 12.8M u32
    unsigned* kvbuf = q_bf + 12800000;                  // 25.6M u32
    unsigned* efbuf = kvbuf + 25600000;                 // 25.6M u32
    int* cnt      = (int*)(efbuf + 25600000);           // 200000
    int* offsets  = cnt + 200000;                       // 210000
    int* csr_src  = offsets + 210000;                   // 800000
    int* csr_ee   = csr_src + 800000;                   // 800000
    unsigned short* WfA = (unsigned short*)(csr_ee + 800000);  // 49152 bf16
    unsigned short* WfB = WfA + 49152;                  // 49152 bf16
    float* bfA    = (float*)(WfB + 49152);              // 384
    float* bfB    = bfA + 384;                          // 384
    int* bsum     = (int*)(bfB + 384);                  // 256
    int* bbase    = bsum + 256;                         // 256
    unsigned short* Wet = (unsigned short*)(bbase + 256); // 12288 bf16

    (void)hipMemsetAsync(cnt, 0, (size_t)200000 * 4, stream);

    // CSR build
    count_kernel<<<(2 * EE + 255) / 256, 256, 0, stream>>>(eiAB, eiBA, cnt);
    scan1_kernel<<<196, 1024, 0, stream>>>(cnt, offsets, bsum);
    scan2_kernel<<<1, 256, 0, stream>>>(bsum, bbase, 196);
    scan3_kernel<<<196, 1024, 0, stream>>>(offsets, bbase, cnt);
    fill_kernel<<<(2 * EE + 255) / 256, 256, 0, stream>>>(eiAB, eiBA, cnt, csr_src, csr_ee);

    // weight prep
    fusew_kernel<<<768, 128, 0, stream>>>(W_kqv_A, b_kqv_A, W_kqv_B, b_kqv_B,
                                          Wk_rel, Wv_rel, WfA, bfA, WfB, bfB);
    wedget_kernel<<<64, 192, 0, stream>>>(W_edge, Wet);

    // MFMA kqv (A+B): NA/BM = 3125 exact
    const int nblkA = NA / BM;
    const int nblkB = NB / BM;
    kqv_mfma_kernel<<<nblkA + nblkB, 256, 0, stream>>>(x_A, x_B, WfA, WfB, bfA, bfB,
                                                       q_bf, kvbuf, nblkA);

    // edge features, wave-synchronous (AB+BA): 50000 wave-tiles / 4 per block
    edgefeat_wave_kernel<<<12500, 256, 0, stream>>>(lu_A, lu_B, eiAB, eiBA,
                                                    t_AB, t_BA, msg_AB, msg_BA,
                                                    time_w, time_b, Wet, b_edge, efbuf);

    gather_kernel<<<NTOT / 16, 256, 0, stream>>>(q_bf, (const uint4*)kvbuf, efbuf,
                                                 offsets, csr_src, csr_ee,
                                                 p_rel_AB, p_rel_BA, (unsigned*)out);

    // MFMA out-projection (A+B)
    proj_mfma_kernel<<<2 * 1563, 256, 0, stream>>>((const short*)out,
                                                   W_out_A, b_out_A, W_out_B, b_out_B,
                                                   x_A, x_B, skip_A, skip_B, out, 1563);
}